// Round 12
// baseline (215.352 us; speedup 1.0000x reference)
//
#include <hip/hip_runtime.h>
#include <cstdint>
#include <cstddef>

// Problem constants (fixed by setup_inputs)
#define QQ 8192       // Z*Y*X
#define CDIM 256
#define NV 9520
#define NLVL 4
#define NPTS 4
#define NHEAD 8
// levels: (h,w) = (64,112),(32,56),(16,28),(8,14); starts 0,7168,8960,9408

typedef __attribute__((ext_vector_type(8))) short short8;
typedef __attribute__((ext_vector_type(4))) float f32x4;
typedef __attribute__((ext_vector_type(2))) float f32x2;

__device__ __forceinline__ unsigned short f2bf(float f)
{
    unsigned u = __float_as_uint(f);
    unsigned r = (u + 0x7fffu + ((u >> 16) & 1u)) >> 16;   // RNE
    return (unsigned short)r;
}
__device__ __forceinline__ unsigned pk2bf(float a, float b)
{
    return (unsigned)f2bf(a) | ((unsigned)f2bf(b) << 16);
}
__device__ __forceinline__ float bf2f(unsigned short u)
{
    return __uint_as_float(((unsigned)u) << 16);
}

// ---- weight transposes + bias concat + mask sniff, ONE kernel ---------------
// grid 1025:
//  [0,256)    Wt_v rows          (Wv^T)
//  [256,512)  Wt_oa rows 0-255   (Woff^T)
//  [512,640)  Wt_oa rows 256-383 (Watt^T)
//  [640,768)  Wt_oa rows 384-511 (zero pad) + bias pad
//  [768,1024) Wt_o rows          (Wo^T)
//  1024       mask dtype sniffer
__global__ void pack_weights_detect_kernel(
    const float* __restrict__ Wv,
    const float* __restrict__ Woff, const float* __restrict__ boff,
    const float* __restrict__ Watt, const float* __restrict__ batt,
    const float* __restrict__ Wo,
    const unsigned int* __restrict__ maskw,
    unsigned short* __restrict__ Wt_v,
    unsigned short* __restrict__ Wt_oa,
    unsigned short* __restrict__ Wt_o,
    float* __restrict__ bias_oa,
    int* __restrict__ flag)
{
    const int n = blockIdx.x, k = threadIdx.x;
    if (n < 256) {
        Wt_v[n * 256 + k] = f2bf(Wv[(size_t)k * 256 + n]);
    } else if (n < 512) {
        const int c = n - 256;
        Wt_oa[c * 256 + k] = f2bf(Woff[(size_t)k * 256 + c]);
        if (k == 0) bias_oa[c] = boff[c];
    } else if (n < 640) {
        const int c = n - 512;
        Wt_oa[(256 + c) * 256 + k] = f2bf(Watt[(size_t)k * 128 + c]);
        if (k == 0) bias_oa[256 + c] = batt[c];
    } else if (n < 768) {
        const int c = n - 640;
        Wt_oa[(384 + c) * 256 + k] = 0;
        if (k == 0) bias_oa[384 + c] = 0.f;
    } else if (n < 1024) {
        const int c = n - 768;
        Wt_o[c * 256 + k] = f2bf(Wo[(size_t)k * 256 + c]);
    } else {
        __shared__ int notI32, notF32;
        if (k == 0) { notI32 = 0; notF32 = 0; }
        __syncthreads();
        for (int i = k; i < 1024; i += 256) {
            unsigned v = maskw[i];
            if (v > 1u) notI32 = 1;
            if (v != 0u && v != 0x3F800000u) notF32 = 1;
        }
        __syncthreads();
        if (k == 0) *flag = (!notI32) ? 1 : ((!notF32) ? 2 : 0);
    }
}

// ------------ mega MFMA GEMM: one launch for Wv / Woff / Watt products -------
// All roles: A f32 (M x 256), B = bf16 transposed weights (256 x 256), K=256.
// Tile 128x256, 512 thr / 8 waves (2x4), wave tile 64x64 = 4x4 frags 16x16x32.
// role 0 [0,595):   v_proj(bf16) = value @ Wt_v + bv   (LDS-staged stores)
// role 1 [595,723): offatt[:,0:256)(bf16,ldc 384) = query @ Woff + boff
// role 2 [723,851): offatt[:,256:384)(bf16) = query @ [Watt|pad] + batt (gn<128)
__global__ __launch_bounds__(512) void mega_gemm_kernel(
    const float* __restrict__ value, const float* __restrict__ query,
    const unsigned short* __restrict__ Wt_v,
    const unsigned short* __restrict__ Wt_oa,
    const float* __restrict__ bv, const float* __restrict__ bias_oa,
    unsigned short* __restrict__ v_proj, unsigned short* __restrict__ offatt)
{
    __shared__ unsigned short As[128 * 64];   // 16 KB
    __shared__ unsigned short Bs[256 * 64];   // 32 KB
    const int bid = blockIdx.x;
    int role, m0;
    const float* A;
    const unsigned short* Bt;
    if (bid < 595)      { role = 0; m0 = bid * 128;         A = value; Bt = Wt_v; }
    else if (bid < 723) { role = 1; m0 = (bid - 595) * 128; A = query; Bt = Wt_oa; }
    else                { role = 2; m0 = (bid - 723) * 128; A = query; Bt = Wt_oa + 256 * 256; }

    const int tid  = threadIdx.x;
    const int lane = tid & 63;
    const int wave = tid >> 6;                // 0..7
    const int wm = wave >> 2, wn = wave & 3;  // 2 x 4
    const int lr = lane & 15, g = lane >> 4;

    f32x4 acc[4][4];
    #pragma unroll
    for (int mi = 0; mi < 4; ++mi)
        #pragma unroll
        for (int ni = 0; ni < 4; ++ni)
            acc[mi][ni] = (f32x4){0.f, 0.f, 0.f, 0.f};

    for (int kt = 0; kt < 4; ++kt) {          // K = 256 = 4 x 64
        uint4 ra[2], rb[4];
        #pragma unroll
        for (int it = 0; it < 2; ++it) {      // A: 1024 16B-blocks / 512 thr
            const int fb  = it * 512 + tid;
            const int row = fb >> 3, kb = fb & 7;
            const float* p = A + (size_t)(m0 + row) * 256 + kt * 64 + kb * 8;
            float4 f0 = *(const float4*)p;
            float4 f1 = *(const float4*)(p + 4);
            ra[it] = make_uint4(pk2bf(f0.x, f0.y), pk2bf(f0.z, f0.w),
                                pk2bf(f1.x, f1.y), pk2bf(f1.z, f1.w));
        }
        #pragma unroll
        for (int it = 0; it < 4; ++it) {      // B: 2048 blocks / 512 thr
            const int fb  = it * 512 + tid;
            const int row = fb >> 3, kb = fb & 7;
            rb[it] = *(const uint4*)(Bt + (size_t)row * 256 + kt * 64 + kb * 8);
        }
        __syncthreads();
        #pragma unroll
        for (int it = 0; it < 2; ++it) {
            const int fb  = it * 512 + tid;
            const int row = fb >> 3, kb = fb & 7;
            *(uint4*)&As[row * 64 + ((kb ^ (row & 7)) << 3)] = ra[it];
        }
        #pragma unroll
        for (int it = 0; it < 4; ++it) {
            const int fb  = it * 512 + tid;
            const int row = fb >> 3, kb = fb & 7;
            *(uint4*)&Bs[row * 64 + ((kb ^ (row & 7)) << 3)] = rb[it];
        }
        __syncthreads();
        #pragma unroll
        for (int kk = 0; kk < 2; ++kk) {
            const int kb = kk * 4 + g;
            short8 af[4], bf[4];
            #pragma unroll
            for (int mi = 0; mi < 4; ++mi) {
                const int row = wm * 64 + mi * 16 + lr;
                af[mi] = *(const short8*)&As[row * 64 + ((kb ^ (row & 7)) << 3)];
            }
            #pragma unroll
            for (int ni = 0; ni < 4; ++ni) {
                const int row = wn * 64 + ni * 16 + lr;
                bf[ni] = *(const short8*)&Bs[row * 64 + ((kb ^ (row & 7)) << 3)];
            }
            #pragma unroll
            for (int mi = 0; mi < 4; ++mi)
                #pragma unroll
                for (int ni = 0; ni < 4; ++ni)
                    acc[mi][ni] = __builtin_amdgcn_mfma_f32_16x16x32_bf16(
                        af[mi], bf[ni], acc[mi][ni], 0, 0, 0);
        }
    }

    // epilogue (role-uniform branches)
    float bcol[4];
    #pragma unroll
    for (int ni = 0; ni < 4; ++ni) {
        const int gn = wn * 64 + ni * 16 + lr;
        bcol[ni] = (role == 0) ? bv[gn]
                 : (role == 1) ? bias_oa[gn] : bias_oa[256 + gn];
    }
    if (role == 0) {
        // stage bf16 tile through LDS (reuse Bs) -> coalesced uint4 stores
        #pragma unroll
        for (int half = 0; half < 2; ++half) {
            __syncthreads();
            if ((wn >> 1) == half) {
                const int wc = wn & 1;
                #pragma unroll
                for (int mi = 0; mi < 4; ++mi)
                    #pragma unroll
                    for (int j = 0; j < 4; ++j) {
                        const int r = wm * 64 + mi * 16 + g * 4 + j;
                        #pragma unroll
                        for (int ni = 0; ni < 4; ++ni) {
                            const int col = wc * 64 + ni * 16 + lr;
                            Bs[r * 128 + col] = f2bf(acc[mi][ni][j] + bcol[ni]);
                        }
                    }
            }
            __syncthreads();
            #pragma unroll
            for (int i = 0; i < 4; ++i) {
                const int f = i * 512 + tid;       // 2048 uint4
                const int r = f >> 4, c16 = f & 15;
                *(uint4*)(v_proj + (size_t)(m0 + r) * 256 + half * 128 + c16 * 8) =
                    *(const uint4*)&Bs[r * 128 + c16 * 8];
            }
        }
    } else {
        #pragma unroll
        for (int mi = 0; mi < 4; ++mi) {
            #pragma unroll
            for (int j = 0; j < 4; ++j) {
                const int gm = m0 + wm * 64 + mi * 16 + g * 4 + j;
                #pragma unroll
                for (int ni = 0; ni < 4; ++ni) {
                    const int gn = wn * 64 + ni * 16 + lr;
                    const float r = acc[mi][ni][j] + bcol[ni];
                    if (role == 1)
                        offatt[(size_t)gm * 384 + gn] = f2bf(r);
                    else if (gn < 128)
                        offatt[(size_t)gm * 384 + 256 + gn] = f2bf(r);
                }
            }
        }
    }
}

// ------------ Wo + residual/mask final GEMM, tile 64x256, 256 thr ------------
__global__ __launch_bounds__(256) void wo_final_kernel(
    const unsigned short* __restrict__ S,     // (16384,256) bf16
    const unsigned short* __restrict__ Wt_o,  // (256,256) bf16 transposed
    const float* __restrict__ query,
    const float* __restrict__ bo,
    const float* __restrict__ cnts,
    float* __restrict__ out)
{
    __shared__ unsigned short As[64 * 64];    // 8 KB
    __shared__ unsigned short Bs[256 * 64];   // 32 KB
    const int tid  = threadIdx.x;
    const int lane = tid & 63;
    const int wn   = tid >> 6;                // 0..3 (N column group)
    const int lr = lane & 15, g = lane >> 4;
    const int m0 = blockIdx.x * 64;

    f32x4 acc[4][4];
    #pragma unroll
    for (int mi = 0; mi < 4; ++mi)
        #pragma unroll
        for (int ni = 0; ni < 4; ++ni)
            acc[mi][ni] = (f32x4){0.f, 0.f, 0.f, 0.f};

    for (int kt = 0; kt < 4; ++kt) {
        uint4 ra[2], rb[8];
        #pragma unroll
        for (int it = 0; it < 2; ++it) {      // A: 512 blocks / 256 thr
            const int fb  = it * 256 + tid;
            const int row = fb >> 3, kb = fb & 7;
            ra[it] = *(const uint4*)(S + (size_t)(m0 + row) * 256 + kt * 64 + kb * 8);
        }
        #pragma unroll
        for (int it = 0; it < 8; ++it) {      // B: 2048 blocks / 256 thr
            const int fb  = it * 256 + tid;
            const int row = fb >> 3, kb = fb & 7;
            rb[it] = *(const uint4*)(Wt_o + (size_t)row * 256 + kt * 64 + kb * 8);
        }
        __syncthreads();
        #pragma unroll
        for (int it = 0; it < 2; ++it) {
            const int fb  = it * 256 + tid;
            const int row = fb >> 3, kb = fb & 7;
            *(uint4*)&As[row * 64 + ((kb ^ (row & 7)) << 3)] = ra[it];
        }
        #pragma unroll
        for (int it = 0; it < 8; ++it) {
            const int fb  = it * 256 + tid;
            const int row = fb >> 3, kb = fb & 7;
            *(uint4*)&Bs[row * 64 + ((kb ^ (row & 7)) << 3)] = rb[it];
        }
        __syncthreads();
        #pragma unroll
        for (int kk = 0; kk < 2; ++kk) {
            const int kb = kk * 4 + g;
            short8 af[4], bf[4];
            #pragma unroll
            for (int mi = 0; mi < 4; ++mi) {
                const int row = mi * 16 + lr;
                af[mi] = *(const short8*)&As[row * 64 + ((kb ^ (row & 7)) << 3)];
            }
            #pragma unroll
            for (int ni = 0; ni < 4; ++ni) {
                const int row = wn * 64 + ni * 16 + lr;
                bf[ni] = *(const short8*)&Bs[row * 64 + ((kb ^ (row & 7)) << 3)];
            }
            #pragma unroll
            for (int mi = 0; mi < 4; ++mi)
                #pragma unroll
                for (int ni = 0; ni < 4; ++ni)
                    acc[mi][ni] = __builtin_amdgcn_mfma_f32_16x16x32_bf16(
                        af[mi], bf[ni], acc[mi][ni], 0, 0, 0);
        }
    }

    float bcol[4];
    #pragma unroll
    for (int ni = 0; ni < 4; ++ni)
        bcol[ni] = bo[wn * 64 + ni * 16 + lr];
    #pragma unroll
    for (int mi = 0; mi < 4; ++mi) {
        #pragma unroll
        for (int j = 0; j < 4; ++j) {
            const int gm = m0 + mi * 16 + g * 4 + j;
            const float sm = cnts[gm];
            const float inv = 1.f / fmaxf(sm, 1.f);
            #pragma unroll
            for (int ni = 0; ni < 4; ++ni) {
                const int gn = wn * 64 + ni * 16 + lr;
                const float qv = query[(size_t)gm * CDIM + gn] + bcol[ni];
                out[(size_t)gm * CDIM + gn] = (sm * qv + acc[mi][ni][j]) * inv;
            }
        }
    }
}

__device__ __forceinline__ float read_mask(const void* p, int f, size_t i)
{
    if (f == 1) return (float)((const int*)p)[i];
    if (f == 2) return ((const float*)p)[i];
    return (float)((const unsigned char*)p)[i];
}

// -------- fused softmax + deformable sampling + masked reduce over N ---------
// One 256-thr block per (b,q); wave n (0..3) handles view bn = b*4+n.
// Phase 1 (ALL waves, unconditional): inline softmax via 16-lane shfl groups;
//   128 (h,l,p) combos -> LDS.  offatt is bf16.
// Phase 2 (live waves only): lane = h*8+d4 gathers uint2 (4 bf16 ch) per
//   corner via SGPR-base + 32-bit voffset (readfirstlane(bn)); f32x2 accum.
// Reduce: LDS cross-wave sum -> S (bf16), cnts.
__global__ __launch_bounds__(256) void sample_reduce_kernel(
    const unsigned short* __restrict__ v,       // (BN, NV, 256) bf16
    const unsigned short* __restrict__ offatt,  // (B*Q, 384) bf16
    const float* __restrict__ refp,             // (BN, Q, 2)
    const void* __restrict__ maskp,             // (BN, Q) bool
    const int* __restrict__ flag,
    unsigned short* __restrict__ S,             // (B*Q, 256) bf16
    float* __restrict__ cnts)                   // (B*Q)
{
    __shared__ int4   sidx[4][NHEAD][17];
    __shared__ float4 swt[4][NHEAD][17];
    __shared__ float  red[4][CDIM];
    __shared__ float  smv[4];
    const int tid  = threadIdx.x;
    const int wn   = tid >> 6;           // wave id = view n
    const int lane = tid & 63;
    const int bq   = blockIdx.x;         // B*Q index
    const int b    = bq >> 13;
    const int q    = bq & (QQ - 1);
    const int bn   = b * 4 + wn;

    const float mn = read_mask(maskp, *flag, (size_t)bn * QQ + q);
    if (lane == 0) smv[wn] = mn;

    const unsigned short* oa = offatt + (size_t)bq * 384;
    const float rx = refp[((size_t)bn * QQ + q) * 2 + 0];
    const float ry = refp[((size_t)bn * QQ + q) * 2 + 1];

    // ---- phase 1: 2 combos per lane; inline softmax over 16-lane groups ----
    #pragma unroll
    for (int cc = 0; cc < 2; ++cc) {
        const int c = lane + cc * 64;        // c = h*16 + l*4 + p
        const int hcomb = c >> 4;
        const int pcomb = c & 15;
        const int l = (c >> 2) & 3;
        const int hh = 64 >> l;
        const int ww = 112 >> l;
        const int s  = (l > 0 ? 7168 : 0) + (l > 1 ? 1792 : 0) + (l > 2 ? 448 : 0);
        const unsigned offxy = *(const unsigned*)(oa + c * 2);
        const float offx = __uint_as_float(offxy << 16);
        const float offy = __uint_as_float(offxy & 0xffff0000u);
        const float logit = bf2f(oa[256 + c]);
        float mx = logit;
        #pragma unroll
        for (int d = 1; d < 16; d <<= 1) mx = fmaxf(mx, __shfl_xor(mx, d));
        const float e = __expf(logit - mx);
        float se = e;
        #pragma unroll
        for (int d = 1; d < 16; d <<= 1) se += __shfl_xor(se, d);
        const float aw = e / se;

        const float x = rx * (float)ww - 0.5f + offx;
        const float y = ry * (float)hh - 0.5f + offy;
        const float x0f = floorf(x), y0f = floorf(y);
        const float lx = x - x0f, ly = y - y0f;
        const int x0 = (int)x0f, y0 = (int)y0f;
        const int x1 = x0 + 1,  y1 = y0 + 1;
        const bool vx0 = (x0 >= 0) & (x0 < ww);
        const bool vx1 = (x1 >= 0) & (x1 < ww);
        const bool vy0 = (y0 >= 0) & (y0 < hh);
        const bool vy1 = (y1 >= 0) & (y1 < hh);
        const int xc0 = min(max(x0, 0), ww - 1);
        const int xc1 = min(max(x1, 0), ww - 1);
        const int yc0 = min(max(y0, 0), hh - 1);
        const int yc1 = min(max(y1, 0), hh - 1);
        float w00 = (1.f - ly) * (1.f - lx) * aw;
        float w01 = (1.f - ly) * lx * aw;
        float w10 = ly * (1.f - lx) * aw;
        float w11 = ly * lx * aw;
        w00 = (vy0 & vx0) ? w00 : 0.f;
        w01 = (vy0 & vx1) ? w01 : 0.f;
        w10 = (vy1 & vx0) ? w10 : 0.f;
        w11 = (vy1 & vx1) ? w11 : 0.f;
        sidx[wn][hcomb][pcomb] = make_int4(s + yc0 * ww + xc0, s + yc0 * ww + xc1,
                                           s + yc1 * ww + xc0, s + yc1 * ww + xc1);
        swt[wn][hcomb][pcomb]  = make_float4(w00, w01, w10, w11);
    }
    // no barrier: phase 2 reads only this wave's [wn] slices (intra-wave dep)

    // ---- phase 2 (live waves only): gather. lane = h*8 + d4 ----
    // SGPR base via readfirstlane(bn) -> global_load with 32-bit voffset:
    // byte offset = (pix << 9) + laneoff*8, one v_lshl_add per corner.
    f32x2 acc01 = (f32x2){0.f, 0.f};
    f32x2 acc23 = (f32x2){0.f, 0.f};
    if (mn != 0.f) {
        const int h  = lane >> 3;
        const int d4 = lane & 7;
        const int lo8 = (h * 8 + d4) * 8;    // byte offset within 512B pixel row
        const int bnu = __builtin_amdgcn_readfirstlane(bn);
        const char* vbase = (const char*)(v + (size_t)bnu * NV * CDIM);
        #pragma unroll 4
        for (int p = 0; p < 16; ++p) {
            const int4   id = sidx[wn][h][p];
            const float4 wt = swt[wn][h][p];
            const uint2 g00 = *(const uint2*)(vbase + (unsigned)((id.x << 9) + lo8));
            const uint2 g01 = *(const uint2*)(vbase + (unsigned)((id.y << 9) + lo8));
            const uint2 g10 = *(const uint2*)(vbase + (unsigned)((id.z << 9) + lo8));
            const uint2 g11 = *(const uint2*)(vbase + (unsigned)((id.w << 9) + lo8));
            #define BFLO(u) __uint_as_float((u) << 16)
            #define BFHI(u) __uint_as_float((u) & 0xffff0000u)
            const f32x2 w00 = (f32x2){wt.x, wt.x};
            const f32x2 w01 = (f32x2){wt.y, wt.y};
            const f32x2 w10 = (f32x2){wt.z, wt.z};
            const f32x2 w11 = (f32x2){wt.w, wt.w};
            acc01 += w00 * (f32x2){BFLO(g00.x), BFHI(g00.x)};
            acc23 += w00 * (f32x2){BFLO(g00.y), BFHI(g00.y)};
            acc01 += w01 * (f32x2){BFLO(g01.x), BFHI(g01.x)};
            acc23 += w01 * (f32x2){BFLO(g01.y), BFHI(g01.y)};
            acc01 += w10 * (f32x2){BFLO(g10.x), BFHI(g10.x)};
            acc23 += w10 * (f32x2){BFLO(g10.y), BFHI(g10.y)};
            acc01 += w11 * (f32x2){BFLO(g11.x), BFHI(g11.x)};
            acc23 += w11 * (f32x2){BFLO(g11.y), BFHI(g11.y)};
            #undef BFLO
            #undef BFHI
        }
    }
    *(float4*)&red[wn][lane * 4] =
        make_float4(acc01.x, acc01.y, acc23.x, acc23.y);
    __syncthreads();

    const float ssum = red[0][tid] + red[1][tid] + red[2][tid] + red[3][tid];
    S[(size_t)bq * CDIM + tid] = f2bf(ssum);
    if (tid == 0) cnts[bq] = smv[0] + smv[1] + smv[2] + smv[3];
}

extern "C" void kernel_launch(void* const* d_in, const int* in_sizes, int n_in,
                              void* d_out, int out_size, void* d_ws, size_t ws_size,
                              hipStream_t stream)
{
    (void)in_sizes; (void)n_in; (void)out_size; (void)ws_size;
    const float* query = (const float*)d_in[0];   // (16384,256)
    const float* value = (const float*)d_in[1];   // (8,9520,256)
    const float* refp  = (const float*)d_in[2];   // (8,8192,2)
    const void*  maskp = d_in[3];                 // (8,8192) bool
    const float* Wv    = (const float*)d_in[6];
    const float* bv    = (const float*)d_in[7];
    const float* Woff  = (const float*)d_in[8];   // (256,256)
    const float* boff  = (const float*)d_in[9];
    const float* Watt  = (const float*)d_in[10];  // (256,128)
    const float* batt  = (const float*)d_in[11];
    const float* Wo    = (const float*)d_in[12];
    const float* bo    = (const float*)d_in[13];
    float* out = (float*)d_out;
    char* ws = (char*)d_ws;

    // workspace layout (bytes)
    unsigned short* v_proj  = (unsigned short*)(ws + 0);          // 38,993,920
    unsigned short* offatt  = (unsigned short*)(ws + 38993920);   // 12,582,912
    unsigned short* S_bf16  = (unsigned short*)(ws + 51576832);   //  8,388,608
    unsigned short* Wt_v    = (unsigned short*)(ws + 59965440);   //    131,072
    unsigned short* Wt_oa   = (unsigned short*)(ws + 60096512);   //    262,144
    unsigned short* Wt_o    = (unsigned short*)(ws + 60358656);   //    131,072
    float*          bias_oa = (float*)(ws + 60489728);            //      2,048
    float*          cnts    = (float*)(ws + 60491776);            //     65,536
    int*            flag    = (int*)(ws + 60557312);              //          4

    pack_weights_detect_kernel<<<1025, 256, 0, stream>>>(
        Wv, Woff, boff, Watt, batt, Wo, (const unsigned int*)maskp,
        Wt_v, Wt_oa, Wt_o, bias_oa, flag);

    // one launch: v_proj (595) + offatt off (128) + offatt att (128)
    mega_gemm_kernel<<<851, 512, 0, stream>>>(
        value, query, Wt_v, Wt_oa, bv, bias_oa, v_proj, offatt);

    // fused softmax + sampling + masked reduce -> S (bf16), cnts
    sample_reduce_kernel<<<16384, 256, 0, stream>>>(
        v_proj, offatt, refp, maskp, flag, S_bf16, cnts);

    // out = (sm*(query+bo) + S@Wo) / max(sm,1)   tile 64x256, full fill
    wo_final_kernel<<<256, 256, 0, stream>>>(
        S_bf16, Wt_o, query, bo, cnts, out);
}

// Round 13
// 203.661 us; speedup vs baseline: 1.0574x; 1.0574x over previous
//
#include <hip/hip_runtime.h>
#include <cstdint>
#include <cstddef>

// Problem constants (fixed by setup_inputs)
#define QQ 8192       // Z*Y*X
#define CDIM 256
#define NV 9520
#define NLVL 4
#define NPTS 4
#define NHEAD 8
// levels: (h,w) = (64,112),(32,56),(16,28),(8,14); starts 0,7168,8960,9408

typedef __attribute__((ext_vector_type(8))) short short8;
typedef __attribute__((ext_vector_type(4))) float f32x4;
typedef __attribute__((ext_vector_type(2))) float f32x2;

__device__ __forceinline__ unsigned short f2bf(float f)
{
    unsigned u = __float_as_uint(f);
    unsigned r = (u + 0x7fffu + ((u >> 16) & 1u)) >> 16;   // RNE
    return (unsigned short)r;
}
__device__ __forceinline__ unsigned pk2bf(float a, float b)
{
    return (unsigned)f2bf(a) | ((unsigned)f2bf(b) << 16);
}
__device__ __forceinline__ float bf2f(unsigned short u)
{
    return __uint_as_float(((unsigned)u) << 16);
}

// ---- weight transposes + bias concat + mask sniff, ONE kernel ---------------
// grid 1025:
//  [0,256)    Wt_v rows          (Wv^T)
//  [256,512)  Wt_oa rows 0-255   (Woff^T)
//  [512,640)  Wt_oa rows 256-383 (Watt^T)
//  [640,768)  Wt_oa rows 384-511 (zero pad) + bias pad
//  [768,1024) Wt_o rows          (Wo^T)
//  1024       mask dtype sniffer
__global__ void pack_weights_detect_kernel(
    const float* __restrict__ Wv,
    const float* __restrict__ Woff, const float* __restrict__ boff,
    const float* __restrict__ Watt, const float* __restrict__ batt,
    const float* __restrict__ Wo,
    const unsigned int* __restrict__ maskw,
    unsigned short* __restrict__ Wt_v,
    unsigned short* __restrict__ Wt_oa,
    unsigned short* __restrict__ Wt_o,
    float* __restrict__ bias_oa,
    int* __restrict__ flag)
{
    const int n = blockIdx.x, k = threadIdx.x;
    if (n < 256) {
        Wt_v[n * 256 + k] = f2bf(Wv[(size_t)k * 256 + n]);
    } else if (n < 512) {
        const int c = n - 256;
        Wt_oa[c * 256 + k] = f2bf(Woff[(size_t)k * 256 + c]);
        if (k == 0) bias_oa[c] = boff[c];
    } else if (n < 640) {
        const int c = n - 512;
        Wt_oa[(256 + c) * 256 + k] = f2bf(Watt[(size_t)k * 128 + c]);
        if (k == 0) bias_oa[256 + c] = batt[c];
    } else if (n < 768) {
        const int c = n - 640;
        Wt_oa[(384 + c) * 256 + k] = 0;
        if (k == 0) bias_oa[384 + c] = 0.f;
    } else if (n < 1024) {
        const int c = n - 768;
        Wt_o[c * 256 + k] = f2bf(Wo[(size_t)k * 256 + c]);
    } else {
        __shared__ int notI32, notF32;
        if (k == 0) { notI32 = 0; notF32 = 0; }
        __syncthreads();
        for (int i = k; i < 1024; i += 256) {
            unsigned v = maskw[i];
            if (v > 1u) notI32 = 1;
            if (v != 0u && v != 0x3F800000u) notF32 = 1;
        }
        __syncthreads();
        if (k == 0) *flag = (!notI32) ? 1 : ((!notF32) ? 2 : 0);
    }
}

// ------------ mega MFMA GEMM: one launch for Wv / Woff / Watt products -------
// All roles: A f32 (M x 256), B = bf16 transposed weights (256 x 256), K=256.
// Tile 128x256, 512 thr / 8 waves (2x4), wave tile 64x64 = 4x4 frags 16x16x32.
// role 0 [0,595):   v_proj(bf16) = value @ Wt_v + bv   (LDS-staged stores)
// role 1 [595,723): offatt[:,0:256)(bf16,ldc 384) = query @ Woff + boff
// role 2 [723,851): offatt[:,256:384)(bf16) = query @ [Watt|pad] + batt (gn<128)
__global__ __launch_bounds__(512) void mega_gemm_kernel(
    const float* __restrict__ value, const float* __restrict__ query,
    const unsigned short* __restrict__ Wt_v,
    const unsigned short* __restrict__ Wt_oa,
    const float* __restrict__ bv, const float* __restrict__ bias_oa,
    unsigned short* __restrict__ v_proj, unsigned short* __restrict__ offatt)
{
    __shared__ unsigned short As[128 * 64];   // 16 KB
    __shared__ unsigned short Bs[256 * 64];   // 32 KB
    const int bid = blockIdx.x;
    int role, m0;
    const float* A;
    const unsigned short* Bt;
    if (bid < 595)      { role = 0; m0 = bid * 128;         A = value; Bt = Wt_v; }
    else if (bid < 723) { role = 1; m0 = (bid - 595) * 128; A = query; Bt = Wt_oa; }
    else                { role = 2; m0 = (bid - 723) * 128; A = query; Bt = Wt_oa + 256 * 256; }

    const int tid  = threadIdx.x;
    const int lane = tid & 63;
    const int wave = tid >> 6;                // 0..7
    const int wm = wave >> 2, wn = wave & 3;  // 2 x 4
    const int lr = lane & 15, g = lane >> 4;

    f32x4 acc[4][4];
    #pragma unroll
    for (int mi = 0; mi < 4; ++mi)
        #pragma unroll
        for (int ni = 0; ni < 4; ++ni)
            acc[mi][ni] = (f32x4){0.f, 0.f, 0.f, 0.f};

    for (int kt = 0; kt < 4; ++kt) {          // K = 256 = 4 x 64
        uint4 ra[2], rb[4];
        #pragma unroll
        for (int it = 0; it < 2; ++it) {      // A: 1024 16B-blocks / 512 thr
            const int fb  = it * 512 + tid;
            const int row = fb >> 3, kb = fb & 7;
            const float* p = A + (size_t)(m0 + row) * 256 + kt * 64 + kb * 8;
            float4 f0 = *(const float4*)p;
            float4 f1 = *(const float4*)(p + 4);
            ra[it] = make_uint4(pk2bf(f0.x, f0.y), pk2bf(f0.z, f0.w),
                                pk2bf(f1.x, f1.y), pk2bf(f1.z, f1.w));
        }
        #pragma unroll
        for (int it = 0; it < 4; ++it) {      // B: 2048 blocks / 512 thr
            const int fb  = it * 512 + tid;
            const int row = fb >> 3, kb = fb & 7;
            rb[it] = *(const uint4*)(Bt + (size_t)row * 256 + kt * 64 + kb * 8);
        }
        __syncthreads();
        #pragma unroll
        for (int it = 0; it < 2; ++it) {
            const int fb  = it * 512 + tid;
            const int row = fb >> 3, kb = fb & 7;
            *(uint4*)&As[row * 64 + ((kb ^ (row & 7)) << 3)] = ra[it];
        }
        #pragma unroll
        for (int it = 0; it < 4; ++it) {
            const int fb  = it * 512 + tid;
            const int row = fb >> 3, kb = fb & 7;
            *(uint4*)&Bs[row * 64 + ((kb ^ (row & 7)) << 3)] = rb[it];
        }
        __syncthreads();
        #pragma unroll
        for (int kk = 0; kk < 2; ++kk) {
            const int kb = kk * 4 + g;
            short8 af[4], bf[4];
            #pragma unroll
            for (int mi = 0; mi < 4; ++mi) {
                const int row = wm * 64 + mi * 16 + lr;
                af[mi] = *(const short8*)&As[row * 64 + ((kb ^ (row & 7)) << 3)];
            }
            #pragma unroll
            for (int ni = 0; ni < 4; ++ni) {
                const int row = wn * 64 + ni * 16 + lr;
                bf[ni] = *(const short8*)&Bs[row * 64 + ((kb ^ (row & 7)) << 3)];
            }
            #pragma unroll
            for (int mi = 0; mi < 4; ++mi)
                #pragma unroll
                for (int ni = 0; ni < 4; ++ni)
                    acc[mi][ni] = __builtin_amdgcn_mfma_f32_16x16x32_bf16(
                        af[mi], bf[ni], acc[mi][ni], 0, 0, 0);
        }
    }

    // epilogue (role-uniform branches)
    float bcol[4];
    #pragma unroll
    for (int ni = 0; ni < 4; ++ni) {
        const int gn = wn * 64 + ni * 16 + lr;
        bcol[ni] = (role == 0) ? bv[gn]
                 : (role == 1) ? bias_oa[gn] : bias_oa[256 + gn];
    }
    if (role == 0) {
        // stage bf16 tile through LDS (reuse Bs) -> coalesced uint4 stores
        #pragma unroll
        for (int half = 0; half < 2; ++half) {
            __syncthreads();
            if ((wn >> 1) == half) {
                const int wc = wn & 1;
                #pragma unroll
                for (int mi = 0; mi < 4; ++mi)
                    #pragma unroll
                    for (int j = 0; j < 4; ++j) {
                        const int r = wm * 64 + mi * 16 + g * 4 + j;
                        #pragma unroll
                        for (int ni = 0; ni < 4; ++ni) {
                            const int col = wc * 64 + ni * 16 + lr;
                            Bs[r * 128 + col] = f2bf(acc[mi][ni][j] + bcol[ni]);
                        }
                    }
            }
            __syncthreads();
            #pragma unroll
            for (int i = 0; i < 4; ++i) {
                const int f = i * 512 + tid;       // 2048 uint4
                const int r = f >> 4, c16 = f & 15;
                *(uint4*)(v_proj + (size_t)(m0 + r) * 256 + half * 128 + c16 * 8) =
                    *(const uint4*)&Bs[r * 128 + c16 * 8];
            }
        }
    } else {
        #pragma unroll
        for (int mi = 0; mi < 4; ++mi) {
            #pragma unroll
            for (int j = 0; j < 4; ++j) {
                const int gm = m0 + wm * 64 + mi * 16 + g * 4 + j;
                #pragma unroll
                for (int ni = 0; ni < 4; ++ni) {
                    const int gn = wn * 64 + ni * 16 + lr;
                    const float r = acc[mi][ni][j] + bcol[ni];
                    if (role == 1)
                        offatt[(size_t)gm * 384 + gn] = f2bf(r);
                    else if (gn < 128)
                        offatt[(size_t)gm * 384 + 256 + gn] = f2bf(r);
                }
            }
        }
    }
}

// ------------ Wo + residual/mask final GEMM, tile 64x256, 256 thr ------------
__global__ __launch_bounds__(256) void wo_final_kernel(
    const unsigned short* __restrict__ S,     // (16384,256) bf16
    const unsigned short* __restrict__ Wt_o,  // (256,256) bf16 transposed
    const float* __restrict__ query,
    const float* __restrict__ bo,
    const float* __restrict__ cnts,
    float* __restrict__ out)
{
    __shared__ unsigned short As[64 * 64];    // 8 KB
    __shared__ unsigned short Bs[256 * 64];   // 32 KB
    const int tid  = threadIdx.x;
    const int lane = tid & 63;
    const int wn   = tid >> 6;                // 0..3 (N column group)
    const int lr = lane & 15, g = lane >> 4;
    const int m0 = blockIdx.x * 64;

    f32x4 acc[4][4];
    #pragma unroll
    for (int mi = 0; mi < 4; ++mi)
        #pragma unroll
        for (int ni = 0; ni < 4; ++ni)
            acc[mi][ni] = (f32x4){0.f, 0.f, 0.f, 0.f};

    for (int kt = 0; kt < 4; ++kt) {
        uint4 ra[2], rb[8];
        #pragma unroll
        for (int it = 0; it < 2; ++it) {      // A: 512 blocks / 256 thr
            const int fb  = it * 256 + tid;
            const int row = fb >> 3, kb = fb & 7;
            ra[it] = *(const uint4*)(S + (size_t)(m0 + row) * 256 + kt * 64 + kb * 8);
        }
        #pragma unroll
        for (int it = 0; it < 8; ++it) {      // B: 2048 blocks / 256 thr
            const int fb  = it * 256 + tid;
            const int row = fb >> 3, kb = fb & 7;
            rb[it] = *(const uint4*)(Wt_o + (size_t)row * 256 + kt * 64 + kb * 8);
        }
        __syncthreads();
        #pragma unroll
        for (int it = 0; it < 2; ++it) {
            const int fb  = it * 256 + tid;
            const int row = fb >> 3, kb = fb & 7;
            *(uint4*)&As[row * 64 + ((kb ^ (row & 7)) << 3)] = ra[it];
        }
        #pragma unroll
        for (int it = 0; it < 8; ++it) {
            const int fb  = it * 256 + tid;
            const int row = fb >> 3, kb = fb & 7;
            *(uint4*)&Bs[row * 64 + ((kb ^ (row & 7)) << 3)] = rb[it];
        }
        __syncthreads();
        #pragma unroll
        for (int kk = 0; kk < 2; ++kk) {
            const int kb = kk * 4 + g;
            short8 af[4], bf[4];
            #pragma unroll
            for (int mi = 0; mi < 4; ++mi) {
                const int row = mi * 16 + lr;
                af[mi] = *(const short8*)&As[row * 64 + ((kb ^ (row & 7)) << 3)];
            }
            #pragma unroll
            for (int ni = 0; ni < 4; ++ni) {
                const int row = wn * 64 + ni * 16 + lr;
                bf[ni] = *(const short8*)&Bs[row * 64 + ((kb ^ (row & 7)) << 3)];
            }
            #pragma unroll
            for (int mi = 0; mi < 4; ++mi)
                #pragma unroll
                for (int ni = 0; ni < 4; ++ni)
                    acc[mi][ni] = __builtin_amdgcn_mfma_f32_16x16x32_bf16(
                        af[mi], bf[ni], acc[mi][ni], 0, 0, 0);
        }
    }

    float bcol[4];
    #pragma unroll
    for (int ni = 0; ni < 4; ++ni)
        bcol[ni] = bo[wn * 64 + ni * 16 + lr];
    #pragma unroll
    for (int mi = 0; mi < 4; ++mi) {
        #pragma unroll
        for (int j = 0; j < 4; ++j) {
            const int gm = m0 + mi * 16 + g * 4 + j;
            const float sm = cnts[gm];
            const float inv = 1.f / fmaxf(sm, 1.f);
            #pragma unroll
            for (int ni = 0; ni < 4; ++ni) {
                const int gn = wn * 64 + ni * 16 + lr;
                const float qv = query[(size_t)gm * CDIM + gn] + bcol[ni];
                out[(size_t)gm * CDIM + gn] = (sm * qv + acc[mi][ni][j]) * inv;
            }
        }
    }
}

__device__ __forceinline__ float read_mask(const void* p, int f, size_t i)
{
    if (f == 1) return (float)((const int*)p)[i];
    if (f == 2) return ((const float*)p)[i];
    return (float)((const unsigned char*)p)[i];
}

// -------- fused softmax + deformable sampling + masked reduce over N ---------
// One 256-thr block per (b,q); wave n (0..3) handles view bn = b*4+n.
// Phase 1 (ALL waves, unconditional): inline softmax via 16-lane shfl groups;
//   128 (h,l,p) combos -> LDS.  offatt is bf16.
// Phase 2 (live waves only): lane = h*8+d4 gathers uint2 (4 bf16 ch) per
//   corner; accumulate in f32x2 pairs (v_pk_fma_f32).
// Reduce: LDS cross-wave sum -> S (bf16), cnts.
__global__ __launch_bounds__(256) void sample_reduce_kernel(
    const unsigned short* __restrict__ v,       // (BN, NV, 256) bf16
    const unsigned short* __restrict__ offatt,  // (B*Q, 384) bf16
    const float* __restrict__ refp,             // (BN, Q, 2)
    const void* __restrict__ maskp,             // (BN, Q) bool
    const int* __restrict__ flag,
    unsigned short* __restrict__ S,             // (B*Q, 256) bf16
    float* __restrict__ cnts)                   // (B*Q)
{
    __shared__ int4   sidx[4][NHEAD][17];
    __shared__ float4 swt[4][NHEAD][17];
    __shared__ float  red[4][CDIM];
    __shared__ float  smv[4];
    const int tid  = threadIdx.x;
    const int wn   = tid >> 6;           // wave id = view n
    const int lane = tid & 63;
    const int bq   = blockIdx.x;         // B*Q index
    const int b    = bq >> 13;
    const int q    = bq & (QQ - 1);
    const int bn   = b * 4 + wn;

    const float mn = read_mask(maskp, *flag, (size_t)bn * QQ + q);
    if (lane == 0) smv[wn] = mn;

    const unsigned short* oa = offatt + (size_t)bq * 384;
    const float rx = refp[((size_t)bn * QQ + q) * 2 + 0];
    const float ry = refp[((size_t)bn * QQ + q) * 2 + 1];

    // ---- phase 1: 2 combos per lane; inline softmax over 16-lane groups ----
    #pragma unroll
    for (int cc = 0; cc < 2; ++cc) {
        const int c = lane + cc * 64;        // c = h*16 + l*4 + p
        const int hcomb = c >> 4;
        const int pcomb = c & 15;
        const int l = (c >> 2) & 3;
        const int hh = 64 >> l;
        const int ww = 112 >> l;
        const int s  = (l > 0 ? 7168 : 0) + (l > 1 ? 1792 : 0) + (l > 2 ? 448 : 0);
        const unsigned offxy = *(const unsigned*)(oa + c * 2);
        const float offx = __uint_as_float(offxy << 16);
        const float offy = __uint_as_float(offxy & 0xffff0000u);
        const float logit = bf2f(oa[256 + c]);
        float mx = logit;
        #pragma unroll
        for (int d = 1; d < 16; d <<= 1) mx = fmaxf(mx, __shfl_xor(mx, d));
        const float e = __expf(logit - mx);
        float se = e;
        #pragma unroll
        for (int d = 1; d < 16; d <<= 1) se += __shfl_xor(se, d);
        const float aw = e / se;

        const float x = rx * (float)ww - 0.5f + offx;
        const float y = ry * (float)hh - 0.5f + offy;
        const float x0f = floorf(x), y0f = floorf(y);
        const float lx = x - x0f, ly = y - y0f;
        const int x0 = (int)x0f, y0 = (int)y0f;
        const int x1 = x0 + 1,  y1 = y0 + 1;
        const bool vx0 = (x0 >= 0) & (x0 < ww);
        const bool vx1 = (x1 >= 0) & (x1 < ww);
        const bool vy0 = (y0 >= 0) & (y0 < hh);
        const bool vy1 = (y1 >= 0) & (y1 < hh);
        const int xc0 = min(max(x0, 0), ww - 1);
        const int xc1 = min(max(x1, 0), ww - 1);
        const int yc0 = min(max(y0, 0), hh - 1);
        const int yc1 = min(max(y1, 0), hh - 1);
        float w00 = (1.f - ly) * (1.f - lx) * aw;
        float w01 = (1.f - ly) * lx * aw;
        float w10 = ly * (1.f - lx) * aw;
        float w11 = ly * lx * aw;
        w00 = (vy0 & vx0) ? w00 : 0.f;
        w01 = (vy0 & vx1) ? w01 : 0.f;
        w10 = (vy1 & vx0) ? w10 : 0.f;
        w11 = (vy1 & vx1) ? w11 : 0.f;
        sidx[wn][hcomb][pcomb] = make_int4(s + yc0 * ww + xc0, s + yc0 * ww + xc1,
                                           s + yc1 * ww + xc0, s + yc1 * ww + xc1);
        swt[wn][hcomb][pcomb]  = make_float4(w00, w01, w10, w11);
    }
    // no barrier: phase 2 reads only this wave's [wn] slices (intra-wave dep)

    // ---- phase 2 (live waves only): gather. lane = h*8 + d4 ----
    f32x2 acc01 = (f32x2){0.f, 0.f};
    f32x2 acc23 = (f32x2){0.f, 0.f};
    if (mn != 0.f) {
        const int h  = lane >> 3;
        const int d4 = lane & 7;
        const int laneoff = h * 8 + d4;  // uint2 units within pixel
        const uint2* vb = (const uint2*)(v + (size_t)bn * NV * CDIM);
        #pragma unroll 4
        for (int p = 0; p < 16; ++p) {
            const int4   id = sidx[wn][h][p];
            const float4 wt = swt[wn][h][p];
            const uint2 g00 = vb[(size_t)(id.x * 64 + laneoff)];
            const uint2 g01 = vb[(size_t)(id.y * 64 + laneoff)];
            const uint2 g10 = vb[(size_t)(id.z * 64 + laneoff)];
            const uint2 g11 = vb[(size_t)(id.w * 64 + laneoff)];
            #define BFLO(u) __uint_as_float((u) << 16)
            #define BFHI(u) __uint_as_float((u) & 0xffff0000u)
            const f32x2 w00 = (f32x2){wt.x, wt.x};
            const f32x2 w01 = (f32x2){wt.y, wt.y};
            const f32x2 w10 = (f32x2){wt.z, wt.z};
            const f32x2 w11 = (f32x2){wt.w, wt.w};
            acc01 += w00 * (f32x2){BFLO(g00.x), BFHI(g00.x)};
            acc23 += w00 * (f32x2){BFLO(g00.y), BFHI(g00.y)};
            acc01 += w01 * (f32x2){BFLO(g01.x), BFHI(g01.x)};
            acc23 += w01 * (f32x2){BFLO(g01.y), BFHI(g01.y)};
            acc01 += w10 * (f32x2){BFLO(g10.x), BFHI(g10.x)};
            acc23 += w10 * (f32x2){BFLO(g10.y), BFHI(g10.y)};
            acc01 += w11 * (f32x2){BFLO(g11.x), BFHI(g11.x)};
            acc23 += w11 * (f32x2){BFLO(g11.y), BFHI(g11.y)};
            #undef BFLO
            #undef BFHI
        }
    }
    *(float4*)&red[wn][lane * 4] =
        make_float4(acc01.x, acc01.y, acc23.x, acc23.y);
    __syncthreads();

    const float ssum = red[0][tid] + red[1][tid] + red[2][tid] + red[3][tid];
    S[(size_t)bq * CDIM + tid] = f2bf(ssum);
    if (tid == 0) cnts[bq] = smv[0] + smv[1] + smv[2] + smv[3];
}

extern "C" void kernel_launch(void* const* d_in, const int* in_sizes, int n_in,
                              void* d_out, int out_size, void* d_ws, size_t ws_size,
                              hipStream_t stream)
{
    (void)in_sizes; (void)n_in; (void)out_size; (void)ws_size;
    const float* query = (const float*)d_in[0];   // (16384,256)
    const float* value = (const float*)d_in[1];   // (8,9520,256)
    const float* refp  = (const float*)d_in[2];   // (8,8192,2)
    const void*  maskp = d_in[3];                 // (8,8192) bool
    const float* Wv    = (const float*)d_in[6];
    const float* bv    = (const float*)d_in[7];
    const float* Woff  = (const float*)d_in[8];   // (256,256)
    const float* boff  = (const float*)d_in[9];
    const float* Watt  = (const float*)d_in[10];  // (256,128)
    const float* batt  = (const float*)d_in[11];
    const float* Wo    = (const float*)d_in[12];
    const float* bo    = (const float*)d_in[13];
    float* out = (float*)d_out;
    char* ws = (char*)d_ws;

    // workspace layout (bytes)
    unsigned short* v_proj  = (unsigned short*)(ws + 0);          // 38,993,920
    unsigned short* offatt  = (unsigned short*)(ws + 38993920);   // 12,582,912
    unsigned short* S_bf16  = (unsigned short*)(ws + 51576832);   //  8,388,608
    unsigned short* Wt_v    = (unsigned short*)(ws + 59965440);   //    131,072
    unsigned short* Wt_oa   = (unsigned short*)(ws + 60096512);   //    262,144
    unsigned short* Wt_o    = (unsigned short*)(ws + 60358656);   //    131,072
    float*          bias_oa = (float*)(ws + 60489728);            //      2,048
    float*          cnts    = (float*)(ws + 60491776);            //     65,536
    int*            flag    = (int*)(ws + 60557312);              //          4

    pack_weights_detect_kernel<<<1025, 256, 0, stream>>>(
        Wv, Woff, boff, Watt, batt, Wo, (const unsigned int*)maskp,
        Wt_v, Wt_oa, Wt_o, bias_oa, flag);

    // one launch: v_proj (595) + offatt off (128) + offatt att (128)
    mega_gemm_kernel<<<851, 512, 0, stream>>>(
        value, query, Wt_v, Wt_oa, bv, bias_oa, v_proj, offatt);

    // fused softmax + sampling + masked reduce -> S (bf16), cnts
    sample_reduce_kernel<<<16384, 256, 0, stream>>>(
        v_proj, offatt, refp, maskp, flag, S_bf16, cnts);

    // out = (sm*(query+bo) + S@Wo) / max(sm,1)   tile 64x256, full fill
    wo_final_kernel<<<256, 256, 0, stream>>>(
        S_bf16, Wt_o, query, bo, cnts, out);
}

// Round 14
// 201.874 us; speedup vs baseline: 1.0668x; 1.0089x over previous
//
#include <hip/hip_runtime.h>
#include <cstdint>
#include <cstddef>

// Problem constants (fixed by setup_inputs)
#define QQ 8192       // Z*Y*X
#define CDIM 256
#define NV 9520
#define NLVL 4
#define NPTS 4
#define NHEAD 8
// levels: (h,w) = (64,112),(32,56),(16,28),(8,14); starts 0,7168,8960,9408

typedef __attribute__((ext_vector_type(8))) short short8;
typedef __attribute__((ext_vector_type(4))) float f32x4;
typedef __attribute__((ext_vector_type(2))) float f32x2;

__device__ __forceinline__ unsigned short f2bf(float f)
{
    unsigned u = __float_as_uint(f);
    unsigned r = (u + 0x7fffu + ((u >> 16) & 1u)) >> 16;   // RNE
    return (unsigned short)r;
}
__device__ __forceinline__ unsigned pk2bf(float a, float b)
{
    return (unsigned)f2bf(a) | ((unsigned)f2bf(b) << 16);
}
__device__ __forceinline__ float bf2f(unsigned short u)
{
    return __uint_as_float(((unsigned)u) << 16);
}

// ---- weight transposes + bias concat + mask sniff, ONE kernel ---------------
// grid 1025:
//  [0,256)    Wt_v rows          (Wv^T)
//  [256,512)  Wt_oa rows 0-255   (Woff^T)
//  [512,640)  Wt_oa rows 256-383 (Watt^T)
//  [640,768)  Wt_oa rows 384-511 (zero pad) + bias pad
//  [768,1024) Wt_o rows          (Wo^T)
//  1024       mask dtype sniffer
__global__ void pack_weights_detect_kernel(
    const float* __restrict__ Wv,
    const float* __restrict__ Woff, const float* __restrict__ boff,
    const float* __restrict__ Watt, const float* __restrict__ batt,
    const float* __restrict__ Wo,
    const unsigned int* __restrict__ maskw,
    unsigned short* __restrict__ Wt_v,
    unsigned short* __restrict__ Wt_oa,
    unsigned short* __restrict__ Wt_o,
    float* __restrict__ bias_oa,
    int* __restrict__ flag)
{
    const int n = blockIdx.x, k = threadIdx.x;
    if (n < 256) {
        Wt_v[n * 256 + k] = f2bf(Wv[(size_t)k * 256 + n]);
    } else if (n < 512) {
        const int c = n - 256;
        Wt_oa[c * 256 + k] = f2bf(Woff[(size_t)k * 256 + c]);
        if (k == 0) bias_oa[c] = boff[c];
    } else if (n < 640) {
        const int c = n - 512;
        Wt_oa[(256 + c) * 256 + k] = f2bf(Watt[(size_t)k * 128 + c]);
        if (k == 0) bias_oa[256 + c] = batt[c];
    } else if (n < 768) {
        const int c = n - 640;
        Wt_oa[(384 + c) * 256 + k] = 0;
        if (k == 0) bias_oa[384 + c] = 0.f;
    } else if (n < 1024) {
        const int c = n - 768;
        Wt_o[c * 256 + k] = f2bf(Wo[(size_t)k * 256 + c]);
    } else {
        __shared__ int notI32, notF32;
        if (k == 0) { notI32 = 0; notF32 = 0; }
        __syncthreads();
        for (int i = k; i < 1024; i += 256) {
            unsigned v = maskw[i];
            if (v > 1u) notI32 = 1;
            if (v != 0u && v != 0x3F800000u) notF32 = 1;
        }
        __syncthreads();
        if (k == 0) *flag = (!notI32) ? 1 : ((!notF32) ? 2 : 0);
    }
}

// ------------ mega MFMA GEMM: one launch for Wv / Woff / Watt products -------
// All roles: A f32 (M x 256), B = bf16 transposed weights (256 x 256), K=256.
// Tile 128x256, 512 thr / 8 waves (2x4), wave tile 64x64 = 4x4 frags 16x16x32.
// role 0 [0,595):   v_proj(bf16) = value @ Wt_v + bv   (LDS-staged stores)
// role 1 [595,723): offatt[:,0:256)(bf16,ldc 384) = query @ Woff + boff
// role 2 [723,851): offatt[:,256:384)(bf16) = query @ [Watt|pad] + batt (gn<128)
__global__ __launch_bounds__(512) void mega_gemm_kernel(
    const float* __restrict__ value, const float* __restrict__ query,
    const unsigned short* __restrict__ Wt_v,
    const unsigned short* __restrict__ Wt_oa,
    const float* __restrict__ bv, const float* __restrict__ bias_oa,
    unsigned short* __restrict__ v_proj, unsigned short* __restrict__ offatt)
{
    __shared__ unsigned short As[128 * 64];   // 16 KB
    __shared__ unsigned short Bs[256 * 64];   // 32 KB
    const int bid = blockIdx.x;
    int role, m0;
    const float* A;
    const unsigned short* Bt;
    if (bid < 595)      { role = 0; m0 = bid * 128;         A = value; Bt = Wt_v; }
    else if (bid < 723) { role = 1; m0 = (bid - 595) * 128; A = query; Bt = Wt_oa; }
    else                { role = 2; m0 = (bid - 723) * 128; A = query; Bt = Wt_oa + 256 * 256; }

    const int tid  = threadIdx.x;
    const int lane = tid & 63;
    const int wave = tid >> 6;                // 0..7
    const int wm = wave >> 2, wn = wave & 3;  // 2 x 4
    const int lr = lane & 15, g = lane >> 4;

    f32x4 acc[4][4];
    #pragma unroll
    for (int mi = 0; mi < 4; ++mi)
        #pragma unroll
        for (int ni = 0; ni < 4; ++ni)
            acc[mi][ni] = (f32x4){0.f, 0.f, 0.f, 0.f};

    for (int kt = 0; kt < 4; ++kt) {          // K = 256 = 4 x 64
        uint4 ra[2], rb[4];
        #pragma unroll
        for (int it = 0; it < 2; ++it) {      // A: 1024 16B-blocks / 512 thr
            const int fb  = it * 512 + tid;
            const int row = fb >> 3, kb = fb & 7;
            const float* p = A + (size_t)(m0 + row) * 256 + kt * 64 + kb * 8;
            float4 f0 = *(const float4*)p;
            float4 f1 = *(const float4*)(p + 4);
            ra[it] = make_uint4(pk2bf(f0.x, f0.y), pk2bf(f0.z, f0.w),
                                pk2bf(f1.x, f1.y), pk2bf(f1.z, f1.w));
        }
        #pragma unroll
        for (int it = 0; it < 4; ++it) {      // B: 2048 blocks / 512 thr
            const int fb  = it * 512 + tid;
            const int row = fb >> 3, kb = fb & 7;
            rb[it] = *(const uint4*)(Bt + (size_t)row * 256 + kt * 64 + kb * 8);
        }
        __syncthreads();
        #pragma unroll
        for (int it = 0; it < 2; ++it) {
            const int fb  = it * 512 + tid;
            const int row = fb >> 3, kb = fb & 7;
            *(uint4*)&As[row * 64 + ((kb ^ (row & 7)) << 3)] = ra[it];
        }
        #pragma unroll
        for (int it = 0; it < 4; ++it) {
            const int fb  = it * 512 + tid;
            const int row = fb >> 3, kb = fb & 7;
            *(uint4*)&Bs[row * 64 + ((kb ^ (row & 7)) << 3)] = rb[it];
        }
        __syncthreads();
        #pragma unroll
        for (int kk = 0; kk < 2; ++kk) {
            const int kb = kk * 4 + g;
            short8 af[4], bf[4];
            #pragma unroll
            for (int mi = 0; mi < 4; ++mi) {
                const int row = wm * 64 + mi * 16 + lr;
                af[mi] = *(const short8*)&As[row * 64 + ((kb ^ (row & 7)) << 3)];
            }
            #pragma unroll
            for (int ni = 0; ni < 4; ++ni) {
                const int row = wn * 64 + ni * 16 + lr;
                bf[ni] = *(const short8*)&Bs[row * 64 + ((kb ^ (row & 7)) << 3)];
            }
            #pragma unroll
            for (int mi = 0; mi < 4; ++mi)
                #pragma unroll
                for (int ni = 0; ni < 4; ++ni)
                    acc[mi][ni] = __builtin_amdgcn_mfma_f32_16x16x32_bf16(
                        af[mi], bf[ni], acc[mi][ni], 0, 0, 0);
        }
    }

    // epilogue (role-uniform branches)
    float bcol[4];
    #pragma unroll
    for (int ni = 0; ni < 4; ++ni) {
        const int gn = wn * 64 + ni * 16 + lr;
        bcol[ni] = (role == 0) ? bv[gn]
                 : (role == 1) ? bias_oa[gn] : bias_oa[256 + gn];
    }
    if (role == 0) {
        // stage bf16 tile through LDS (reuse Bs) -> coalesced uint4 stores
        #pragma unroll
        for (int half = 0; half < 2; ++half) {
            __syncthreads();
            if ((wn >> 1) == half) {
                const int wc = wn & 1;
                #pragma unroll
                for (int mi = 0; mi < 4; ++mi)
                    #pragma unroll
                    for (int j = 0; j < 4; ++j) {
                        const int r = wm * 64 + mi * 16 + g * 4 + j;
                        #pragma unroll
                        for (int ni = 0; ni < 4; ++ni) {
                            const int col = wc * 64 + ni * 16 + lr;
                            Bs[r * 128 + col] = f2bf(acc[mi][ni][j] + bcol[ni]);
                        }
                    }
            }
            __syncthreads();
            #pragma unroll
            for (int i = 0; i < 4; ++i) {
                const int f = i * 512 + tid;       // 2048 uint4
                const int r = f >> 4, c16 = f & 15;
                *(uint4*)(v_proj + (size_t)(m0 + r) * 256 + half * 128 + c16 * 8) =
                    *(const uint4*)&Bs[r * 128 + c16 * 8];
            }
        }
    } else {
        #pragma unroll
        for (int mi = 0; mi < 4; ++mi) {
            #pragma unroll
            for (int j = 0; j < 4; ++j) {
                const int gm = m0 + wm * 64 + mi * 16 + g * 4 + j;
                #pragma unroll
                for (int ni = 0; ni < 4; ++ni) {
                    const int gn = wn * 64 + ni * 16 + lr;
                    const float r = acc[mi][ni][j] + bcol[ni];
                    if (role == 1)
                        offatt[(size_t)gm * 384 + gn] = f2bf(r);
                    else if (gn < 128)
                        offatt[(size_t)gm * 384 + 256 + gn] = f2bf(r);
                }
            }
        }
    }
}

// ------------ Wo + residual/mask final GEMM, tile 64x256, 256 thr ------------
__global__ __launch_bounds__(256) void wo_final_kernel(
    const unsigned short* __restrict__ S,     // (16384,256) bf16
    const unsigned short* __restrict__ Wt_o,  // (256,256) bf16 transposed
    const float* __restrict__ query,
    const float* __restrict__ bo,
    const float* __restrict__ cnts,
    float* __restrict__ out)
{
    __shared__ unsigned short As[64 * 64];    // 8 KB
    __shared__ unsigned short Bs[256 * 64];   // 32 KB
    const int tid  = threadIdx.x;
    const int lane = tid & 63;
    const int wn   = tid >> 6;                // 0..3 (N column group)
    const int lr = lane & 15, g = lane >> 4;
    const int m0 = blockIdx.x * 64;

    f32x4 acc[4][4];
    #pragma unroll
    for (int mi = 0; mi < 4; ++mi)
        #pragma unroll
        for (int ni = 0; ni < 4; ++ni)
            acc[mi][ni] = (f32x4){0.f, 0.f, 0.f, 0.f};

    for (int kt = 0; kt < 4; ++kt) {
        uint4 ra[2], rb[8];
        #pragma unroll
        for (int it = 0; it < 2; ++it) {      // A: 512 blocks / 256 thr
            const int fb  = it * 256 + tid;
            const int row = fb >> 3, kb = fb & 7;
            ra[it] = *(const uint4*)(S + (size_t)(m0 + row) * 256 + kt * 64 + kb * 8);
        }
        #pragma unroll
        for (int it = 0; it < 8; ++it) {      // B: 2048 blocks / 256 thr
            const int fb  = it * 256 + tid;
            const int row = fb >> 3, kb = fb & 7;
            rb[it] = *(const uint4*)(Wt_o + (size_t)row * 256 + kt * 64 + kb * 8);
        }
        __syncthreads();
        #pragma unroll
        for (int it = 0; it < 2; ++it) {
            const int fb  = it * 256 + tid;
            const int row = fb >> 3, kb = fb & 7;
            *(uint4*)&As[row * 64 + ((kb ^ (row & 7)) << 3)] = ra[it];
        }
        #pragma unroll
        for (int it = 0; it < 8; ++it) {
            const int fb  = it * 256 + tid;
            const int row = fb >> 3, kb = fb & 7;
            *(uint4*)&Bs[row * 64 + ((kb ^ (row & 7)) << 3)] = rb[it];
        }
        __syncthreads();
        #pragma unroll
        for (int kk = 0; kk < 2; ++kk) {
            const int kb = kk * 4 + g;
            short8 af[4], bf[4];
            #pragma unroll
            for (int mi = 0; mi < 4; ++mi) {
                const int row = mi * 16 + lr;
                af[mi] = *(const short8*)&As[row * 64 + ((kb ^ (row & 7)) << 3)];
            }
            #pragma unroll
            for (int ni = 0; ni < 4; ++ni) {
                const int row = wn * 64 + ni * 16 + lr;
                bf[ni] = *(const short8*)&Bs[row * 64 + ((kb ^ (row & 7)) << 3)];
            }
            #pragma unroll
            for (int mi = 0; mi < 4; ++mi)
                #pragma unroll
                for (int ni = 0; ni < 4; ++ni)
                    acc[mi][ni] = __builtin_amdgcn_mfma_f32_16x16x32_bf16(
                        af[mi], bf[ni], acc[mi][ni], 0, 0, 0);
        }
    }

    float bcol[4];
    #pragma unroll
    for (int ni = 0; ni < 4; ++ni)
        bcol[ni] = bo[wn * 64 + ni * 16 + lr];
    #pragma unroll
    for (int mi = 0; mi < 4; ++mi) {
        #pragma unroll
        for (int j = 0; j < 4; ++j) {
            const int gm = m0 + mi * 16 + g * 4 + j;
            const float sm = cnts[gm];
            const float inv = 1.f / fmaxf(sm, 1.f);
            #pragma unroll
            for (int ni = 0; ni < 4; ++ni) {
                const int gn = wn * 64 + ni * 16 + lr;
                const float qv = query[(size_t)gm * CDIM + gn] + bcol[ni];
                out[(size_t)gm * CDIM + gn] = (sm * qv + acc[mi][ni][j]) * inv;
            }
        }
    }
}

__device__ __forceinline__ float read_mask(const void* p, int f, size_t i)
{
    if (f == 1) return (float)((const int*)p)[i];
    if (f == 2) return ((const float*)p)[i];
    return (float)((const unsigned char*)p)[i];
}

// -------- fused softmax + deformable sampling + masked reduce over N ---------
// One 256-thr block per (b,q); wave n (0..3) handles view bn = b*4+n.
// Phase 1 (ALL waves, unconditional): inline softmax via 16-lane shfl groups;
//   128 (h,l,p) combos -> LDS.  offatt is bf16.
// Phase 2 (live waves only): points in explicit groups of 4 — all 16 corner
//   loads of a group issued into a register array before any FMA (forced
//   loads-in-flight); 4 corner-split accumulators break the FMA dep chain.
// Reduce: LDS cross-wave sum -> S (bf16), cnts.
__global__ __launch_bounds__(256) void sample_reduce_kernel(
    const unsigned short* __restrict__ v,       // (BN, NV, 256) bf16
    const unsigned short* __restrict__ offatt,  // (B*Q, 384) bf16
    const float* __restrict__ refp,             // (BN, Q, 2)
    const void* __restrict__ maskp,             // (BN, Q) bool
    const int* __restrict__ flag,
    unsigned short* __restrict__ S,             // (B*Q, 256) bf16
    float* __restrict__ cnts)                   // (B*Q)
{
    __shared__ int4   sidx[4][NHEAD][17];
    __shared__ float4 swt[4][NHEAD][17];
    __shared__ float  red[4][CDIM];
    __shared__ float  smv[4];
    const int tid  = threadIdx.x;
    const int wn   = tid >> 6;           // wave id = view n
    const int lane = tid & 63;
    const int bq   = blockIdx.x;         // B*Q index
    const int b    = bq >> 13;
    const int q    = bq & (QQ - 1);
    const int bn   = b * 4 + wn;

    const float mn = read_mask(maskp, *flag, (size_t)bn * QQ + q);
    if (lane == 0) smv[wn] = mn;

    const unsigned short* oa = offatt + (size_t)bq * 384;
    const float rx = refp[((size_t)bn * QQ + q) * 2 + 0];
    const float ry = refp[((size_t)bn * QQ + q) * 2 + 1];

    // ---- phase 1: 2 combos per lane; inline softmax over 16-lane groups ----
    #pragma unroll
    for (int cc = 0; cc < 2; ++cc) {
        const int c = lane + cc * 64;        // c = h*16 + l*4 + p
        const int hcomb = c >> 4;
        const int pcomb = c & 15;
        const int l = (c >> 2) & 3;
        const int hh = 64 >> l;
        const int ww = 112 >> l;
        const int s  = (l > 0 ? 7168 : 0) + (l > 1 ? 1792 : 0) + (l > 2 ? 448 : 0);
        const unsigned offxy = *(const unsigned*)(oa + c * 2);
        const float offx = __uint_as_float(offxy << 16);
        const float offy = __uint_as_float(offxy & 0xffff0000u);
        const float logit = bf2f(oa[256 + c]);
        float mx = logit;
        #pragma unroll
        for (int d = 1; d < 16; d <<= 1) mx = fmaxf(mx, __shfl_xor(mx, d));
        const float e = __expf(logit - mx);
        float se = e;
        #pragma unroll
        for (int d = 1; d < 16; d <<= 1) se += __shfl_xor(se, d);
        const float aw = e / se;

        const float x = rx * (float)ww - 0.5f + offx;
        const float y = ry * (float)hh - 0.5f + offy;
        const float x0f = floorf(x), y0f = floorf(y);
        const float lx = x - x0f, ly = y - y0f;
        const int x0 = (int)x0f, y0 = (int)y0f;
        const int x1 = x0 + 1,  y1 = y0 + 1;
        const bool vx0 = (x0 >= 0) & (x0 < ww);
        const bool vx1 = (x1 >= 0) & (x1 < ww);
        const bool vy0 = (y0 >= 0) & (y0 < hh);
        const bool vy1 = (y1 >= 0) & (y1 < hh);
        const int xc0 = min(max(x0, 0), ww - 1);
        const int xc1 = min(max(x1, 0), ww - 1);
        const int yc0 = min(max(y0, 0), hh - 1);
        const int yc1 = min(max(y1, 0), hh - 1);
        float w00 = (1.f - ly) * (1.f - lx) * aw;
        float w01 = (1.f - ly) * lx * aw;
        float w10 = ly * (1.f - lx) * aw;
        float w11 = ly * lx * aw;
        w00 = (vy0 & vx0) ? w00 : 0.f;
        w01 = (vy0 & vx1) ? w01 : 0.f;
        w10 = (vy1 & vx0) ? w10 : 0.f;
        w11 = (vy1 & vx1) ? w11 : 0.f;
        sidx[wn][hcomb][pcomb] = make_int4(s + yc0 * ww + xc0, s + yc0 * ww + xc1,
                                           s + yc1 * ww + xc0, s + yc1 * ww + xc1);
        swt[wn][hcomb][pcomb]  = make_float4(w00, w01, w10, w11);
    }
    // no barrier: phase 2 reads only this wave's [wn] slices (intra-wave dep)

    // ---- phase 2 (live waves only): gather. lane = h*8 + d4 ----
    // 4-point groups: all 16 corner loads issued before FMAs; 4 corner-split
    // accumulator pairs (c01[k], c23[k]) keep dep chains at 16.
    f32x2 c01[4], c23[4];
    #pragma unroll
    for (int k = 0; k < 4; ++k) { c01[k] = (f32x2){0.f, 0.f}; c23[k] = (f32x2){0.f, 0.f}; }
    if (mn != 0.f) {
        const int h  = lane >> 3;
        const int d4 = lane & 7;
        const int laneoff = h * 8 + d4;  // uint2 units within pixel
        const uint2* vb = (const uint2*)(v + (size_t)bn * NV * CDIM);
        #pragma unroll
        for (int pb = 0; pb < 4; ++pb) {
            uint2  gld[16];
            float4 wts[4];
            #pragma unroll
            for (int j = 0; j < 4; ++j) {
                const int p = pb * 4 + j;
                const int4 id = sidx[wn][h][p];
                wts[j] = swt[wn][h][p];
                gld[j * 4 + 0] = vb[(size_t)(id.x * 64 + laneoff)];
                gld[j * 4 + 1] = vb[(size_t)(id.y * 64 + laneoff)];
                gld[j * 4 + 2] = vb[(size_t)(id.z * 64 + laneoff)];
                gld[j * 4 + 3] = vb[(size_t)(id.w * 64 + laneoff)];
            }
            #pragma unroll
            for (int j = 0; j < 4; ++j) {
                const float4 wt = wts[j];
                const float wa[4] = {wt.x, wt.y, wt.z, wt.w};
                #pragma unroll
                for (int cidx = 0; cidx < 4; ++cidx) {
                    const uint2 gg = gld[j * 4 + cidx];
                    const f32x2 wv = (f32x2){wa[cidx], wa[cidx]};
                    #define BFLO(u) __uint_as_float((u) << 16)
                    #define BFHI(u) __uint_as_float((u) & 0xffff0000u)
                    c01[cidx] += wv * (f32x2){BFLO(gg.x), BFHI(gg.x)};
                    c23[cidx] += wv * (f32x2){BFLO(gg.y), BFHI(gg.y)};
                    #undef BFLO
                    #undef BFHI
                }
            }
        }
    }
    const f32x2 acc01 = (c01[0] + c01[1]) + (c01[2] + c01[3]);
    const f32x2 acc23 = (c23[0] + c23[1]) + (c23[2] + c23[3]);
    *(float4*)&red[wn][lane * 4] =
        make_float4(acc01.x, acc01.y, acc23.x, acc23.y);
    __syncthreads();

    const float ssum = red[0][tid] + red[1][tid] + red[2][tid] + red[3][tid];
    S[(size_t)bq * CDIM + tid] = f2bf(ssum);
    if (tid == 0) cnts[bq] = smv[0] + smv[1] + smv[2] + smv[3];
}

extern "C" void kernel_launch(void* const* d_in, const int* in_sizes, int n_in,
                              void* d_out, int out_size, void* d_ws, size_t ws_size,
                              hipStream_t stream)
{
    (void)in_sizes; (void)n_in; (void)out_size; (void)ws_size;
    const float* query = (const float*)d_in[0];   // (16384,256)
    const float* value = (const float*)d_in[1];   // (8,9520,256)
    const float* refp  = (const float*)d_in[2];   // (8,8192,2)
    const void*  maskp = d_in[3];                 // (8,8192) bool
    const float* Wv    = (const float*)d_in[6];
    const float* bv    = (const float*)d_in[7];
    const float* Woff  = (const float*)d_in[8];   // (256,256)
    const float* boff  = (const float*)d_in[9];
    const float* Watt  = (const float*)d_in[10];  // (256,128)
    const float* batt  = (const float*)d_in[11];
    const float* Wo    = (const float*)d_in[12];
    const float* bo    = (const float*)d_in[13];
    float* out = (float*)d_out;
    char* ws = (char*)d_ws;

    // workspace layout (bytes)
    unsigned short* v_proj  = (unsigned short*)(ws + 0);          // 38,993,920
    unsigned short* offatt  = (unsigned short*)(ws + 38993920);   // 12,582,912
    unsigned short* S_bf16  = (unsigned short*)(ws + 51576832);   //  8,388,608
    unsigned short* Wt_v    = (unsigned short*)(ws + 59965440);   //    131,072
    unsigned short* Wt_oa   = (unsigned short*)(ws + 60096512);   //    262,144
    unsigned short* Wt_o    = (unsigned short*)(ws + 60358656);   //    131,072
    float*          bias_oa = (float*)(ws + 60489728);            //      2,048
    float*          cnts    = (float*)(ws + 60491776);            //     65,536
    int*            flag    = (int*)(ws + 60557312);              //          4

    pack_weights_detect_kernel<<<1025, 256, 0, stream>>>(
        Wv, Woff, boff, Watt, batt, Wo, (const unsigned int*)maskp,
        Wt_v, Wt_oa, Wt_o, bias_oa, flag);

    // one launch: v_proj (595) + offatt off (128) + offatt att (128)
    mega_gemm_kernel<<<851, 512, 0, stream>>>(
        value, query, Wt_v, Wt_oa, bv, bias_oa, v_proj, offatt);

    // fused softmax + sampling + masked reduce -> S (bf16), cnts
    sample_reduce_kernel<<<16384, 256, 0, stream>>>(
        v_proj, offatt, refp, maskp, flag, S_bf16, cnts);

    // out = (sm*(query+bo) + S@Wo) / max(sm,1)   tile 64x256, full fill
    wo_final_kernel<<<256, 256, 0, stream>>>(
        S_bf16, Wt_o, query, bo, cnts, out);
}

// Round 15
// 200.314 us; speedup vs baseline: 1.0751x; 1.0078x over previous
//
#include <hip/hip_runtime.h>
#include <cstdint>
#include <cstddef>

// Problem constants (fixed by setup_inputs)
#define QQ 8192       // Z*Y*X
#define CDIM 256
#define NV 9520
#define NLVL 4
#define NPTS 4
#define NHEAD 8
// levels: (h,w) = (64,112),(32,56),(16,28),(8,14); starts 0,7168,8960,9408

typedef __attribute__((ext_vector_type(8))) short short8;
typedef __attribute__((ext_vector_type(4))) float f32x4;
typedef __attribute__((ext_vector_type(2))) float f32x2;

__device__ __forceinline__ unsigned short f2bf(float f)
{
    unsigned u = __float_as_uint(f);
    unsigned r = (u + 0x7fffu + ((u >> 16) & 1u)) >> 16;   // RNE
    return (unsigned short)r;
}
__device__ __forceinline__ unsigned pk2bf(float a, float b)
{
    return (unsigned)f2bf(a) | ((unsigned)f2bf(b) << 16);
}
__device__ __forceinline__ float bf2f(unsigned short u)
{
    return __uint_as_float(((unsigned)u) << 16);
}

// ---- weight transposes + bias concat + mask sniff, ONE kernel ---------------
// grid 1025:
//  [0,256)    Wt_v rows          (Wv^T)
//  [256,512)  Wt_oa rows 0-255   (Woff^T)
//  [512,640)  Wt_oa rows 256-383 (Watt^T)
//  [640,768)  Wt_oa rows 384-511 (zero pad) + bias pad
//  [768,1024) Wt_o rows          (Wo^T)
//  1024       mask dtype sniffer
__global__ void pack_weights_detect_kernel(
    const float* __restrict__ Wv,
    const float* __restrict__ Woff, const float* __restrict__ boff,
    const float* __restrict__ Watt, const float* __restrict__ batt,
    const float* __restrict__ Wo,
    const unsigned int* __restrict__ maskw,
    unsigned short* __restrict__ Wt_v,
    unsigned short* __restrict__ Wt_oa,
    unsigned short* __restrict__ Wt_o,
    float* __restrict__ bias_oa,
    int* __restrict__ flag)
{
    const int n = blockIdx.x, k = threadIdx.x;
    if (n < 256) {
        Wt_v[n * 256 + k] = f2bf(Wv[(size_t)k * 256 + n]);
    } else if (n < 512) {
        const int c = n - 256;
        Wt_oa[c * 256 + k] = f2bf(Woff[(size_t)k * 256 + c]);
        if (k == 0) bias_oa[c] = boff[c];
    } else if (n < 640) {
        const int c = n - 512;
        Wt_oa[(256 + c) * 256 + k] = f2bf(Watt[(size_t)k * 128 + c]);
        if (k == 0) bias_oa[256 + c] = batt[c];
    } else if (n < 768) {
        const int c = n - 640;
        Wt_oa[(384 + c) * 256 + k] = 0;
        if (k == 0) bias_oa[384 + c] = 0.f;
    } else if (n < 1024) {
        const int c = n - 768;
        Wt_o[c * 256 + k] = f2bf(Wo[(size_t)k * 256 + c]);
    } else {
        __shared__ int notI32, notF32;
        if (k == 0) { notI32 = 0; notF32 = 0; }
        __syncthreads();
        for (int i = k; i < 1024; i += 256) {
            unsigned v = maskw[i];
            if (v > 1u) notI32 = 1;
            if (v != 0u && v != 0x3F800000u) notF32 = 1;
        }
        __syncthreads();
        if (k == 0) *flag = (!notI32) ? 1 : ((!notF32) ? 2 : 0);
    }
}

// ------------ mega MFMA GEMM: one launch for Wv / Woff / Watt products -------
// All roles: A f32 (M x 256), B = bf16 transposed weights (256 x 256), K=256.
// Tile 128x256, 512 thr / 8 waves (2x4), wave tile 64x64 = 4x4 frags 16x16x32.
// role 0 [0,595):   v_proj(bf16) = value @ Wt_v + bv   (LDS-staged stores)
// role 1 [595,723): offatt[:,0:256)(bf16,ldc 384) = query @ Woff + boff
// role 2 [723,851): offatt[:,256:384)(bf16) = query @ [Watt|pad] + batt (gn<128)
__global__ __launch_bounds__(512) void mega_gemm_kernel(
    const float* __restrict__ value, const float* __restrict__ query,
    const unsigned short* __restrict__ Wt_v,
    const unsigned short* __restrict__ Wt_oa,
    const float* __restrict__ bv, const float* __restrict__ bias_oa,
    unsigned short* __restrict__ v_proj, unsigned short* __restrict__ offatt)
{
    __shared__ unsigned short As[128 * 64];   // 16 KB
    __shared__ unsigned short Bs[256 * 64];   // 32 KB
    const int bid = blockIdx.x;
    int role, m0;
    const float* A;
    const unsigned short* Bt;
    if (bid < 595)      { role = 0; m0 = bid * 128;         A = value; Bt = Wt_v; }
    else if (bid < 723) { role = 1; m0 = (bid - 595) * 128; A = query; Bt = Wt_oa; }
    else                { role = 2; m0 = (bid - 723) * 128; A = query; Bt = Wt_oa + 256 * 256; }

    const int tid  = threadIdx.x;
    const int lane = tid & 63;
    const int wave = tid >> 6;                // 0..7
    const int wm = wave >> 2, wn = wave & 3;  // 2 x 4
    const int lr = lane & 15, g = lane >> 4;

    f32x4 acc[4][4];
    #pragma unroll
    for (int mi = 0; mi < 4; ++mi)
        #pragma unroll
        for (int ni = 0; ni < 4; ++ni)
            acc[mi][ni] = (f32x4){0.f, 0.f, 0.f, 0.f};

    for (int kt = 0; kt < 4; ++kt) {          // K = 256 = 4 x 64
        uint4 ra[2], rb[4];
        #pragma unroll
        for (int it = 0; it < 2; ++it) {      // A: 1024 16B-blocks / 512 thr
            const int fb  = it * 512 + tid;
            const int row = fb >> 3, kb = fb & 7;
            const float* p = A + (size_t)(m0 + row) * 256 + kt * 64 + kb * 8;
            float4 f0 = *(const float4*)p;
            float4 f1 = *(const float4*)(p + 4);
            ra[it] = make_uint4(pk2bf(f0.x, f0.y), pk2bf(f0.z, f0.w),
                                pk2bf(f1.x, f1.y), pk2bf(f1.z, f1.w));
        }
        #pragma unroll
        for (int it = 0; it < 4; ++it) {      // B: 2048 blocks / 512 thr
            const int fb  = it * 512 + tid;
            const int row = fb >> 3, kb = fb & 7;
            rb[it] = *(const uint4*)(Bt + (size_t)row * 256 + kt * 64 + kb * 8);
        }
        __syncthreads();
        #pragma unroll
        for (int it = 0; it < 2; ++it) {
            const int fb  = it * 512 + tid;
            const int row = fb >> 3, kb = fb & 7;
            *(uint4*)&As[row * 64 + ((kb ^ (row & 7)) << 3)] = ra[it];
        }
        #pragma unroll
        for (int it = 0; it < 4; ++it) {
            const int fb  = it * 512 + tid;
            const int row = fb >> 3, kb = fb & 7;
            *(uint4*)&Bs[row * 64 + ((kb ^ (row & 7)) << 3)] = rb[it];
        }
        __syncthreads();
        #pragma unroll
        for (int kk = 0; kk < 2; ++kk) {
            const int kb = kk * 4 + g;
            short8 af[4], bf[4];
            #pragma unroll
            for (int mi = 0; mi < 4; ++mi) {
                const int row = wm * 64 + mi * 16 + lr;
                af[mi] = *(const short8*)&As[row * 64 + ((kb ^ (row & 7)) << 3)];
            }
            #pragma unroll
            for (int ni = 0; ni < 4; ++ni) {
                const int row = wn * 64 + ni * 16 + lr;
                bf[ni] = *(const short8*)&Bs[row * 64 + ((kb ^ (row & 7)) << 3)];
            }
            #pragma unroll
            for (int mi = 0; mi < 4; ++mi)
                #pragma unroll
                for (int ni = 0; ni < 4; ++ni)
                    acc[mi][ni] = __builtin_amdgcn_mfma_f32_16x16x32_bf16(
                        af[mi], bf[ni], acc[mi][ni], 0, 0, 0);
        }
    }

    // epilogue (role-uniform branches)
    float bcol[4];
    #pragma unroll
    for (int ni = 0; ni < 4; ++ni) {
        const int gn = wn * 64 + ni * 16 + lr;
        bcol[ni] = (role == 0) ? bv[gn]
                 : (role == 1) ? bias_oa[gn] : bias_oa[256 + gn];
    }
    if (role == 0) {
        // stage bf16 tile through LDS (reuse Bs) -> coalesced uint4 stores
        #pragma unroll
        for (int half = 0; half < 2; ++half) {
            __syncthreads();
            if ((wn >> 1) == half) {
                const int wc = wn & 1;
                #pragma unroll
                for (int mi = 0; mi < 4; ++mi)
                    #pragma unroll
                    for (int j = 0; j < 4; ++j) {
                        const int r = wm * 64 + mi * 16 + g * 4 + j;
                        #pragma unroll
                        for (int ni = 0; ni < 4; ++ni) {
                            const int col = wc * 64 + ni * 16 + lr;
                            Bs[r * 128 + col] = f2bf(acc[mi][ni][j] + bcol[ni]);
                        }
                    }
            }
            __syncthreads();
            #pragma unroll
            for (int i = 0; i < 4; ++i) {
                const int f = i * 512 + tid;       // 2048 uint4
                const int r = f >> 4, c16 = f & 15;
                *(uint4*)(v_proj + (size_t)(m0 + r) * 256 + half * 128 + c16 * 8) =
                    *(const uint4*)&Bs[r * 128 + c16 * 8];
            }
        }
    } else {
        #pragma unroll
        for (int mi = 0; mi < 4; ++mi) {
            #pragma unroll
            for (int j = 0; j < 4; ++j) {
                const int gm = m0 + wm * 64 + mi * 16 + g * 4 + j;
                #pragma unroll
                for (int ni = 0; ni < 4; ++ni) {
                    const int gn = wn * 64 + ni * 16 + lr;
                    const float r = acc[mi][ni][j] + bcol[ni];
                    if (role == 1)
                        offatt[(size_t)gm * 384 + gn] = f2bf(r);
                    else if (gn < 128)
                        offatt[(size_t)gm * 384 + 256 + gn] = f2bf(r);
                }
            }
        }
    }
}

// ------------ Wo + residual/mask final GEMM, tile 64x256, 256 thr ------------
__global__ __launch_bounds__(256) void wo_final_kernel(
    const unsigned short* __restrict__ S,     // (16384,256) bf16
    const unsigned short* __restrict__ Wt_o,  // (256,256) bf16 transposed
    const float* __restrict__ query,
    const float* __restrict__ bo,
    const float* __restrict__ cnts,
    float* __restrict__ out)
{
    __shared__ unsigned short As[64 * 64];    // 8 KB
    __shared__ unsigned short Bs[256 * 64];   // 32 KB
    const int tid  = threadIdx.x;
    const int lane = tid & 63;
    const int wn   = tid >> 6;                // 0..3 (N column group)
    const int lr = lane & 15, g = lane >> 4;
    const int m0 = blockIdx.x * 64;

    f32x4 acc[4][4];
    #pragma unroll
    for (int mi = 0; mi < 4; ++mi)
        #pragma unroll
        for (int ni = 0; ni < 4; ++ni)
            acc[mi][ni] = (f32x4){0.f, 0.f, 0.f, 0.f};

    for (int kt = 0; kt < 4; ++kt) {
        uint4 ra[2], rb[8];
        #pragma unroll
        for (int it = 0; it < 2; ++it) {      // A: 512 blocks / 256 thr
            const int fb  = it * 256 + tid;
            const int row = fb >> 3, kb = fb & 7;
            ra[it] = *(const uint4*)(S + (size_t)(m0 + row) * 256 + kt * 64 + kb * 8);
        }
        #pragma unroll
        for (int it = 0; it < 8; ++it) {      // B: 2048 blocks / 256 thr
            const int fb  = it * 256 + tid;
            const int row = fb >> 3, kb = fb & 7;
            rb[it] = *(const uint4*)(Wt_o + (size_t)row * 256 + kt * 64 + kb * 8);
        }
        __syncthreads();
        #pragma unroll
        for (int it = 0; it < 2; ++it) {
            const int fb  = it * 256 + tid;
            const int row = fb >> 3, kb = fb & 7;
            *(uint4*)&As[row * 64 + ((kb ^ (row & 7)) << 3)] = ra[it];
        }
        #pragma unroll
        for (int it = 0; it < 8; ++it) {
            const int fb  = it * 256 + tid;
            const int row = fb >> 3, kb = fb & 7;
            *(uint4*)&Bs[row * 64 + ((kb ^ (row & 7)) << 3)] = rb[it];
        }
        __syncthreads();
        #pragma unroll
        for (int kk = 0; kk < 2; ++kk) {
            const int kb = kk * 4 + g;
            short8 af[4], bf[4];
            #pragma unroll
            for (int mi = 0; mi < 4; ++mi) {
                const int row = mi * 16 + lr;
                af[mi] = *(const short8*)&As[row * 64 + ((kb ^ (row & 7)) << 3)];
            }
            #pragma unroll
            for (int ni = 0; ni < 4; ++ni) {
                const int row = wn * 64 + ni * 16 + lr;
                bf[ni] = *(const short8*)&Bs[row * 64 + ((kb ^ (row & 7)) << 3)];
            }
            #pragma unroll
            for (int mi = 0; mi < 4; ++mi)
                #pragma unroll
                for (int ni = 0; ni < 4; ++ni)
                    acc[mi][ni] = __builtin_amdgcn_mfma_f32_16x16x32_bf16(
                        af[mi], bf[ni], acc[mi][ni], 0, 0, 0);
        }
    }

    float bcol[4];
    #pragma unroll
    for (int ni = 0; ni < 4; ++ni)
        bcol[ni] = bo[wn * 64 + ni * 16 + lr];
    #pragma unroll
    for (int mi = 0; mi < 4; ++mi) {
        #pragma unroll
        for (int j = 0; j < 4; ++j) {
            const int gm = m0 + mi * 16 + g * 4 + j;
            const float sm = cnts[gm];
            const float inv = 1.f / fmaxf(sm, 1.f);
            #pragma unroll
            for (int ni = 0; ni < 4; ++ni) {
                const int gn = wn * 64 + ni * 16 + lr;
                const float qv = query[(size_t)gm * CDIM + gn] + bcol[ni];
                out[(size_t)gm * CDIM + gn] = (sm * qv + acc[mi][ni][j]) * inv;
            }
        }
    }
}

__device__ __forceinline__ float read_mask(const void* p, int f, size_t i)
{
    if (f == 1) return (float)((const int*)p)[i];
    if (f == 2) return ((const float*)p)[i];
    return (float)((const unsigned char*)p)[i];
}

// -------- fused softmax + deformable sampling + masked reduce over N ---------
// One 256-thr block per (b,q); wave n (0..3) handles view bn = b*4+n.
// Phase 1 (ALL waves, unconditional): inline softmax via 16-lane shfl groups;
//   128 (h,l,p) combos -> LDS.  offatt is bf16.
// Phase 2 (live waves only): points in groups of 4; ALL 16 corner loads of a
//   group forced in flight via a register-consuming asm fence before any FMA;
//   4 corner-split accumulators break the FMA dep chain.
// Reduce: LDS cross-wave sum -> S (bf16), cnts.
__global__ __launch_bounds__(256) void sample_reduce_kernel(
    const unsigned short* __restrict__ v,       // (BN, NV, 256) bf16
    const unsigned short* __restrict__ offatt,  // (B*Q, 384) bf16
    const float* __restrict__ refp,             // (BN, Q, 2)
    const void* __restrict__ maskp,             // (BN, Q) bool
    const int* __restrict__ flag,
    unsigned short* __restrict__ S,             // (B*Q, 256) bf16
    float* __restrict__ cnts)                   // (B*Q)
{
    __shared__ int4   sidx[4][NHEAD][17];
    __shared__ float4 swt[4][NHEAD][17];
    __shared__ float  red[4][CDIM];
    __shared__ float  smv[4];
    const int tid  = threadIdx.x;
    const int wn   = tid >> 6;           // wave id = view n
    const int lane = tid & 63;
    const int bq   = blockIdx.x;         // B*Q index
    const int b    = bq >> 13;
    const int q    = bq & (QQ - 1);
    const int bn   = b * 4 + wn;

    const float mn = read_mask(maskp, *flag, (size_t)bn * QQ + q);
    if (lane == 0) smv[wn] = mn;

    const unsigned short* oa = offatt + (size_t)bq * 384;
    const float rx = refp[((size_t)bn * QQ + q) * 2 + 0];
    const float ry = refp[((size_t)bn * QQ + q) * 2 + 1];

    // ---- phase 1: 2 combos per lane; inline softmax over 16-lane groups ----
    #pragma unroll
    for (int cc = 0; cc < 2; ++cc) {
        const int c = lane + cc * 64;        // c = h*16 + l*4 + p
        const int hcomb = c >> 4;
        const int pcomb = c & 15;
        const int l = (c >> 2) & 3;
        const int hh = 64 >> l;
        const int ww = 112 >> l;
        const int s  = (l > 0 ? 7168 : 0) + (l > 1 ? 1792 : 0) + (l > 2 ? 448 : 0);
        const unsigned offxy = *(const unsigned*)(oa + c * 2);
        const float offx = __uint_as_float(offxy << 16);
        const float offy = __uint_as_float(offxy & 0xffff0000u);
        const float logit = bf2f(oa[256 + c]);
        float mx = logit;
        #pragma unroll
        for (int d = 1; d < 16; d <<= 1) mx = fmaxf(mx, __shfl_xor(mx, d));
        const float e = __expf(logit - mx);
        float se = e;
        #pragma unroll
        for (int d = 1; d < 16; d <<= 1) se += __shfl_xor(se, d);
        const float aw = e / se;

        const float x = rx * (float)ww - 0.5f + offx;
        const float y = ry * (float)hh - 0.5f + offy;
        const float x0f = floorf(x), y0f = floorf(y);
        const float lx = x - x0f, ly = y - y0f;
        const int x0 = (int)x0f, y0 = (int)y0f;
        const int x1 = x0 + 1,  y1 = y0 + 1;
        const bool vx0 = (x0 >= 0) & (x0 < ww);
        const bool vx1 = (x1 >= 0) & (x1 < ww);
        const bool vy0 = (y0 >= 0) & (y0 < hh);
        const bool vy1 = (y1 >= 0) & (y1 < hh);
        const int xc0 = min(max(x0, 0), ww - 1);
        const int xc1 = min(max(x1, 0), ww - 1);
        const int yc0 = min(max(y0, 0), hh - 1);
        const int yc1 = min(max(y1, 0), hh - 1);
        float w00 = (1.f - ly) * (1.f - lx) * aw;
        float w01 = (1.f - ly) * lx * aw;
        float w10 = ly * (1.f - lx) * aw;
        float w11 = ly * lx * aw;
        w00 = (vy0 & vx0) ? w00 : 0.f;
        w01 = (vy0 & vx1) ? w01 : 0.f;
        w10 = (vy1 & vx0) ? w10 : 0.f;
        w11 = (vy1 & vx1) ? w11 : 0.f;
        sidx[wn][hcomb][pcomb] = make_int4(s + yc0 * ww + xc0, s + yc0 * ww + xc1,
                                           s + yc1 * ww + xc0, s + yc1 * ww + xc1);
        swt[wn][hcomb][pcomb]  = make_float4(w00, w01, w10, w11);
    }
    // no barrier: phase 2 reads only this wave's [wn] slices (intra-wave dep)

    // ---- phase 2 (live waves only): gather. lane = h*8 + d4 ----
    f32x2 c01[4], c23[4];
    #pragma unroll
    for (int k = 0; k < 4; ++k) { c01[k] = (f32x2){0.f, 0.f}; c23[k] = (f32x2){0.f, 0.f}; }
    if (mn != 0.f) {
        const int h  = lane >> 3;
        const int d4 = lane & 7;
        const int laneoff = h * 8 + d4;  // u64 units within pixel (64 per pixel)
        const unsigned long long* vb =
            (const unsigned long long*)(v + (size_t)bn * NV * CDIM);
        #pragma unroll
        for (int pb = 0; pb < 4; ++pb) {
            unsigned long long gld[16];
            float4 wts[4];
            #pragma unroll
            for (int j = 0; j < 4; ++j) {
                const int p = pb * 4 + j;
                const int4 id = sidx[wn][h][p];
                wts[j] = swt[wn][h][p];
                gld[j * 4 + 0] = vb[(size_t)(id.x * 64 + laneoff)];
                gld[j * 4 + 1] = vb[(size_t)(id.y * 64 + laneoff)];
                gld[j * 4 + 2] = vb[(size_t)(id.z * 64 + laneoff)];
                gld[j * 4 + 3] = vb[(size_t)(id.w * 64 + laneoff)];
            }
            // fence: consume all 16 loaded values -> compiler must issue all
            // 16 loads before the first FMA (forces 16-deep MLP per wave)
            asm volatile("" ::
                "v"(gld[0]),  "v"(gld[1]),  "v"(gld[2]),  "v"(gld[3]),
                "v"(gld[4]),  "v"(gld[5]),  "v"(gld[6]),  "v"(gld[7]),
                "v"(gld[8]),  "v"(gld[9]),  "v"(gld[10]), "v"(gld[11]),
                "v"(gld[12]), "v"(gld[13]), "v"(gld[14]), "v"(gld[15]));
            #pragma unroll
            for (int j = 0; j < 4; ++j) {
                const float4 wt = wts[j];
                const float wa[4] = {wt.x, wt.y, wt.z, wt.w};
                #pragma unroll
                for (int cidx = 0; cidx < 4; ++cidx) {
                    const unsigned long long gg = gld[j * 4 + cidx];
                    const unsigned glo = (unsigned)gg;
                    const unsigned ghi = (unsigned)(gg >> 32);
                    const f32x2 wv = (f32x2){wa[cidx], wa[cidx]};
                    #define BFLO(u) __uint_as_float((u) << 16)
                    #define BFHI(u) __uint_as_float((u) & 0xffff0000u)
                    c01[cidx] += wv * (f32x2){BFLO(glo), BFHI(glo)};
                    c23[cidx] += wv * (f32x2){BFLO(ghi), BFHI(ghi)};
                    #undef BFLO
                    #undef BFHI
                }
            }
        }
    }
    const f32x2 acc01 = (c01[0] + c01[1]) + (c01[2] + c01[3]);
    const f32x2 acc23 = (c23[0] + c23[1]) + (c23[2] + c23[3]);
    *(float4*)&red[wn][lane * 4] =
        make_float4(acc01.x, acc01.y, acc23.x, acc23.y);
    __syncthreads();

    const float ssum = red[0][tid] + red[1][tid] + red[2][tid] + red[3][tid];
    S[(size_t)bq * CDIM + tid] = f2bf(ssum);
    if (tid == 0) cnts[bq] = smv[0] + smv[1] + smv[2] + smv[3];
}

extern "C" void kernel_launch(void* const* d_in, const int* in_sizes, int n_in,
                              void* d_out, int out_size, void* d_ws, size_t ws_size,
                              hipStream_t stream)
{
    (void)in_sizes; (void)n_in; (void)out_size; (void)ws_size;
    const float* query = (const float*)d_in[0];   // (16384,256)
    const float* value = (const float*)d_in[1];   // (8,9520,256)
    const float* refp  = (const float*)d_in[2];   // (8,8192,2)
    const void*  maskp = d_in[3];                 // (8,8192) bool
    const float* Wv    = (const float*)d_in[6];
    const float* bv    = (const float*)d_in[7];
    const float* Woff  = (const float*)d_in[8];   // (256,256)
    const float* boff  = (const float*)d_in[9];
    const float* Watt  = (const float*)d_in[10];  // (256,128)
    const float* batt  = (const float*)d_in[11];
    const float* Wo    = (const float*)d_in[12];
    const float* bo    = (const float*)d_in[13];
    float* out = (float*)d_out;
    char* ws = (char*)d_ws;

    // workspace layout (bytes)
    unsigned short* v_proj  = (unsigned short*)(ws + 0);          // 38,993,920
    unsigned short* offatt  = (unsigned short*)(ws + 38993920);   // 12,582,912
    unsigned short* S_bf16  = (unsigned short*)(ws + 51576832);   //  8,388,608
    unsigned short* Wt_v    = (unsigned short*)(ws + 59965440);   //    131,072
    unsigned short* Wt_oa   = (unsigned short*)(ws + 60096512);   //    262,144
    unsigned short* Wt_o    = (unsigned short*)(ws + 60358656);   //    131,072
    float*          bias_oa = (float*)(ws + 60489728);            //      2,048
    float*          cnts    = (float*)(ws + 60491776);            //     65,536
    int*            flag    = (int*)(ws + 60557312);              //          4

    pack_weights_detect_kernel<<<1025, 256, 0, stream>>>(
        Wv, Woff, boff, Watt, batt, Wo, (const unsigned int*)maskp,
        Wt_v, Wt_oa, Wt_o, bias_oa, flag);

    // one launch: v_proj (595) + offatt off (128) + offatt att (128)
    mega_gemm_kernel<<<851, 512, 0, stream>>>(
        value, query, Wt_v, Wt_oa, bv, bias_oa, v_proj, offatt);

    // fused softmax + sampling + masked reduce -> S (bf16), cnts
    sample_reduce_kernel<<<16384, 256, 0, stream>>>(
        v_proj, offatt, refp, maskp, flag, S_bf16, cnts);

    // out = (sm*(query+bo) + S@Wo) / max(sm,1)   tile 64x256, full fill
    wo_final_kernel<<<256, 256, 0, stream>>>(
        S_bf16, Wt_o, query, bo, cnts, out);
}

// Round 16
// 191.848 us; speedup vs baseline: 1.1225x; 1.0441x over previous
//
#include <hip/hip_runtime.h>
#include <cstdint>
#include <cstddef>

// Problem constants (fixed by setup_inputs)
#define QQ 8192       // Z*Y*X
#define CDIM 256
#define NV 9520
#define NLVL 4
#define NPTS 4
#define NHEAD 8
// levels: (h,w) = (64,112),(32,56),(16,28),(8,14); starts 0,7168,8960,9408
// v_proj layout: HEAD-MAJOR (bn, h, pix, 32ch) bf16 -> 64 B per (h,pix) slice

typedef __attribute__((ext_vector_type(8))) short short8;
typedef __attribute__((ext_vector_type(4))) float f32x4;
typedef __attribute__((ext_vector_type(2))) float f32x2;

__device__ __forceinline__ unsigned short f2bf(float f)
{
    unsigned u = __float_as_uint(f);
    unsigned r = (u + 0x7fffu + ((u >> 16) & 1u)) >> 16;   // RNE
    return (unsigned short)r;
}
__device__ __forceinline__ unsigned pk2bf(float a, float b)
{
    return (unsigned)f2bf(a) | ((unsigned)f2bf(b) << 16);
}
__device__ __forceinline__ float bf2f(unsigned short u)
{
    return __uint_as_float(((unsigned)u) << 16);
}

// ---- weight transposes + bias concat + mask sniff, ONE kernel ---------------
__global__ void pack_weights_detect_kernel(
    const float* __restrict__ Wv,
    const float* __restrict__ Woff, const float* __restrict__ boff,
    const float* __restrict__ Watt, const float* __restrict__ batt,
    const float* __restrict__ Wo,
    const unsigned int* __restrict__ maskw,
    unsigned short* __restrict__ Wt_v,
    unsigned short* __restrict__ Wt_oa,
    unsigned short* __restrict__ Wt_o,
    float* __restrict__ bias_oa,
    int* __restrict__ flag)
{
    const int n = blockIdx.x, k = threadIdx.x;
    if (n < 256) {
        Wt_v[n * 256 + k] = f2bf(Wv[(size_t)k * 256 + n]);
    } else if (n < 512) {
        const int c = n - 256;
        Wt_oa[c * 256 + k] = f2bf(Woff[(size_t)k * 256 + c]);
        if (k == 0) bias_oa[c] = boff[c];
    } else if (n < 640) {
        const int c = n - 512;
        Wt_oa[(256 + c) * 256 + k] = f2bf(Watt[(size_t)k * 128 + c]);
        if (k == 0) bias_oa[256 + c] = batt[c];
    } else if (n < 768) {
        const int c = n - 640;
        Wt_oa[(384 + c) * 256 + k] = 0;
        if (k == 0) bias_oa[384 + c] = 0.f;
    } else if (n < 1024) {
        const int c = n - 768;
        Wt_o[c * 256 + k] = f2bf(Wo[(size_t)k * 256 + c]);
    } else {
        __shared__ int notI32, notF32;
        if (k == 0) { notI32 = 0; notF32 = 0; }
        __syncthreads();
        for (int i = k; i < 1024; i += 256) {
            unsigned v = maskw[i];
            if (v > 1u) notI32 = 1;
            if (v != 0u && v != 0x3F800000u) notF32 = 1;
        }
        __syncthreads();
        if (k == 0) *flag = (!notI32) ? 1 : ((!notF32) ? 2 : 0);
    }
}

// ------------ mega MFMA GEMM: one launch for Wv / Woff / Watt products -------
// role 0 [0,595):   v_proj(bf16, HEAD-MAJOR) = value @ Wt_v + bv (LDS-staged)
// role 1 [595,723): offatt[:,0:256)(bf16,ldc 384) = query @ Woff + boff
// role 2 [723,851): offatt[:,256:384)(bf16) = query @ [Watt|pad] + batt (gn<128)
__global__ __launch_bounds__(512) void mega_gemm_kernel(
    const float* __restrict__ value, const float* __restrict__ query,
    const unsigned short* __restrict__ Wt_v,
    const unsigned short* __restrict__ Wt_oa,
    const float* __restrict__ bv, const float* __restrict__ bias_oa,
    unsigned short* __restrict__ v_proj, unsigned short* __restrict__ offatt)
{
    __shared__ unsigned short As[128 * 64];   // 16 KB
    __shared__ unsigned short Bs[256 * 64];   // 32 KB
    const int bid = blockIdx.x;
    int role, m0;
    const float* A;
    const unsigned short* Bt;
    if (bid < 595)      { role = 0; m0 = bid * 128;         A = value; Bt = Wt_v; }
    else if (bid < 723) { role = 1; m0 = (bid - 595) * 128; A = query; Bt = Wt_oa; }
    else                { role = 2; m0 = (bid - 723) * 128; A = query; Bt = Wt_oa + 256 * 256; }

    const int tid  = threadIdx.x;
    const int lane = tid & 63;
    const int wave = tid >> 6;                // 0..7
    const int wm = wave >> 2, wn = wave & 3;  // 2 x 4
    const int lr = lane & 15, g = lane >> 4;

    f32x4 acc[4][4];
    #pragma unroll
    for (int mi = 0; mi < 4; ++mi)
        #pragma unroll
        for (int ni = 0; ni < 4; ++ni)
            acc[mi][ni] = (f32x4){0.f, 0.f, 0.f, 0.f};

    for (int kt = 0; kt < 4; ++kt) {          // K = 256 = 4 x 64
        uint4 ra[2], rb[4];
        #pragma unroll
        for (int it = 0; it < 2; ++it) {      // A: 1024 16B-blocks / 512 thr
            const int fb  = it * 512 + tid;
            const int row = fb >> 3, kb = fb & 7;
            const float* p = A + (size_t)(m0 + row) * 256 + kt * 64 + kb * 8;
            float4 f0 = *(const float4*)p;
            float4 f1 = *(const float4*)(p + 4);
            ra[it] = make_uint4(pk2bf(f0.x, f0.y), pk2bf(f0.z, f0.w),
                                pk2bf(f1.x, f1.y), pk2bf(f1.z, f1.w));
        }
        #pragma unroll
        for (int it = 0; it < 4; ++it) {      // B: 2048 blocks / 512 thr
            const int fb  = it * 512 + tid;
            const int row = fb >> 3, kb = fb & 7;
            rb[it] = *(const uint4*)(Bt + (size_t)row * 256 + kt * 64 + kb * 8);
        }
        __syncthreads();
        #pragma unroll
        for (int it = 0; it < 2; ++it) {
            const int fb  = it * 512 + tid;
            const int row = fb >> 3, kb = fb & 7;
            *(uint4*)&As[row * 64 + ((kb ^ (row & 7)) << 3)] = ra[it];
        }
        #pragma unroll
        for (int it = 0; it < 4; ++it) {
            const int fb  = it * 512 + tid;
            const int row = fb >> 3, kb = fb & 7;
            *(uint4*)&Bs[row * 64 + ((kb ^ (row & 7)) << 3)] = rb[it];
        }
        __syncthreads();
        #pragma unroll
        for (int kk = 0; kk < 2; ++kk) {
            const int kb = kk * 4 + g;
            short8 af[4], bf[4];
            #pragma unroll
            for (int mi = 0; mi < 4; ++mi) {
                const int row = wm * 64 + mi * 16 + lr;
                af[mi] = *(const short8*)&As[row * 64 + ((kb ^ (row & 7)) << 3)];
            }
            #pragma unroll
            for (int ni = 0; ni < 4; ++ni) {
                const int row = wn * 64 + ni * 16 + lr;
                bf[ni] = *(const short8*)&Bs[row * 64 + ((kb ^ (row & 7)) << 3)];
            }
            #pragma unroll
            for (int mi = 0; mi < 4; ++mi)
                #pragma unroll
                for (int ni = 0; ni < 4; ++ni)
                    acc[mi][ni] = __builtin_amdgcn_mfma_f32_16x16x32_bf16(
                        af[mi], bf[ni], acc[mi][ni], 0, 0, 0);
        }
    }

    // epilogue (role-uniform branches)
    float bcol[4];
    #pragma unroll
    for (int ni = 0; ni < 4; ++ni) {
        const int gn = wn * 64 + ni * 16 + lr;
        bcol[ni] = (role == 0) ? bv[gn]
                 : (role == 1) ? bias_oa[gn] : bias_oa[256 + gn];
    }
    if (role == 0) {
        // stage bf16 half-tile (128 rows x 128 ch) through LDS, then scatter
        // HEAD-MAJOR: dest ((bn*8+h)*9520 + pix)*32ch.  half 0 = heads 0..3.
        #pragma unroll
        for (int half = 0; half < 2; ++half) {
            __syncthreads();
            if ((wn >> 1) == half) {
                const int wc = wn & 1;
                #pragma unroll
                for (int mi = 0; mi < 4; ++mi)
                    #pragma unroll
                    for (int j = 0; j < 4; ++j) {
                        const int r = wm * 64 + mi * 16 + g * 4 + j;
                        #pragma unroll
                        for (int ni = 0; ni < 4; ++ni) {
                            const int col = wc * 64 + ni * 16 + lr;
                            Bs[r * 128 + col] = f2bf(acc[mi][ni][j] + bcol[ni]);
                        }
                    }
            }
            __syncthreads();
            #pragma unroll
            for (int i = 0; i < 4; ++i) {
                const int u  = i * 512 + tid;    // 2048 uint4
                const int hl = u >> 9;           // head-local 0..3
                const int r  = (u >> 2) & 127;
                const int c4 = u & 3;
                const int rowg = m0 + r;
                const unsigned bnq = (unsigned)rowg / 9520u;
                const int pix = rowg - (int)bnq * 9520;
                const int hgl = half * 4 + hl;
                unsigned short* dst = v_proj +
                    (((size_t)(bnq * 8 + hgl) * 9520 + pix) << 5) + c4 * 8;
                *(uint4*)dst = *(const uint4*)&Bs[r * 128 + hl * 32 + c4 * 8];
            }
        }
    } else {
        #pragma unroll
        for (int mi = 0; mi < 4; ++mi) {
            #pragma unroll
            for (int j = 0; j < 4; ++j) {
                const int gm = m0 + wm * 64 + mi * 16 + g * 4 + j;
                #pragma unroll
                for (int ni = 0; ni < 4; ++ni) {
                    const int gn = wn * 64 + ni * 16 + lr;
                    const float r = acc[mi][ni][j] + bcol[ni];
                    if (role == 1)
                        offatt[(size_t)gm * 384 + gn] = f2bf(r);
                    else if (gn < 128)
                        offatt[(size_t)gm * 384 + 256 + gn] = f2bf(r);
                }
            }
        }
    }
}

// ------------ Wo + residual/mask final GEMM, tile 64x256, 256 thr ------------
__global__ __launch_bounds__(256) void wo_final_kernel(
    const unsigned short* __restrict__ S,     // (16384,256) bf16
    const unsigned short* __restrict__ Wt_o,  // (256,256) bf16 transposed
    const float* __restrict__ query,
    const float* __restrict__ bo,
    const float* __restrict__ cnts,
    float* __restrict__ out)
{
    __shared__ unsigned short As[64 * 64];    // 8 KB
    __shared__ unsigned short Bs[256 * 64];   // 32 KB
    const int tid  = threadIdx.x;
    const int lane = tid & 63;
    const int wn   = tid >> 6;                // 0..3 (N column group)
    const int lr = lane & 15, g = lane >> 4;
    const int m0 = blockIdx.x * 64;

    f32x4 acc[4][4];
    #pragma unroll
    for (int mi = 0; mi < 4; ++mi)
        #pragma unroll
        for (int ni = 0; ni < 4; ++ni)
            acc[mi][ni] = (f32x4){0.f, 0.f, 0.f, 0.f};

    for (int kt = 0; kt < 4; ++kt) {
        uint4 ra[2], rb[8];
        #pragma unroll
        for (int it = 0; it < 2; ++it) {      // A: 512 blocks / 256 thr
            const int fb  = it * 256 + tid;
            const int row = fb >> 3, kb = fb & 7;
            ra[it] = *(const uint4*)(S + (size_t)(m0 + row) * 256 + kt * 64 + kb * 8);
        }
        #pragma unroll
        for (int it = 0; it < 8; ++it) {      // B: 2048 blocks / 256 thr
            const int fb  = it * 256 + tid;
            const int row = fb >> 3, kb = fb & 7;
            rb[it] = *(const uint4*)(Wt_o + (size_t)row * 256 + kt * 64 + kb * 8);
        }
        __syncthreads();
        #pragma unroll
        for (int it = 0; it < 2; ++it) {
            const int fb  = it * 256 + tid;
            const int row = fb >> 3, kb = fb & 7;
            *(uint4*)&As[row * 64 + ((kb ^ (row & 7)) << 3)] = ra[it];
        }
        #pragma unroll
        for (int it = 0; it < 8; ++it) {
            const int fb  = it * 256 + tid;
            const int row = fb >> 3, kb = fb & 7;
            *(uint4*)&Bs[row * 64 + ((kb ^ (row & 7)) << 3)] = rb[it];
        }
        __syncthreads();
        #pragma unroll
        for (int kk = 0; kk < 2; ++kk) {
            const int kb = kk * 4 + g;
            short8 af[4], bf[4];
            #pragma unroll
            for (int mi = 0; mi < 4; ++mi) {
                const int row = mi * 16 + lr;
                af[mi] = *(const short8*)&As[row * 64 + ((kb ^ (row & 7)) << 3)];
            }
            #pragma unroll
            for (int ni = 0; ni < 4; ++ni) {
                const int row = wn * 64 + ni * 16 + lr;
                bf[ni] = *(const short8*)&Bs[row * 64 + ((kb ^ (row & 7)) << 3)];
            }
            #pragma unroll
            for (int mi = 0; mi < 4; ++mi)
                #pragma unroll
                for (int ni = 0; ni < 4; ++ni)
                    acc[mi][ni] = __builtin_amdgcn_mfma_f32_16x16x32_bf16(
                        af[mi], bf[ni], acc[mi][ni], 0, 0, 0);
        }
    }

    float bcol[4];
    #pragma unroll
    for (int ni = 0; ni < 4; ++ni)
        bcol[ni] = bo[wn * 64 + ni * 16 + lr];
    #pragma unroll
    for (int mi = 0; mi < 4; ++mi) {
        #pragma unroll
        for (int j = 0; j < 4; ++j) {
            const int gm = m0 + mi * 16 + g * 4 + j;
            const float sm = cnts[gm];
            const float inv = 1.f / fmaxf(sm, 1.f);
            #pragma unroll
            for (int ni = 0; ni < 4; ++ni) {
                const int gn = wn * 64 + ni * 16 + lr;
                const float qv = query[(size_t)gm * CDIM + gn] + bcol[ni];
                out[(size_t)gm * CDIM + gn] = (sm * qv + acc[mi][ni][j]) * inv;
            }
        }
    }
}

__device__ __forceinline__ float read_mask(const void* p, int f, size_t i)
{
    if (f == 1) return (float)((const int*)p)[i];
    if (f == 2) return ((const float*)p)[i];
    return (float)((const unsigned char*)p)[i];
}

// -------- fused softmax + deformable sampling + masked reduce over N ---------
// One 256-thr block per (b,q); wave n (0..3) handles view bn = b*4+n.
// Phase 1 (ALL waves, unconditional): inline softmax via 16-lane shfl groups;
//   128 (h,l,p) combos -> LDS.  offatt is bf16.
// Phase 2 (live waves only): v is HEAD-MAJOR -> x-adjacent corners share
//   128 B cache lines; points in groups of 4 with corner-split accumulators.
// Reduce: LDS cross-wave sum -> S (bf16), cnts.
__global__ __launch_bounds__(256) void sample_reduce_kernel(
    const unsigned short* __restrict__ v,       // (BN, H, NV, 32) bf16
    const unsigned short* __restrict__ offatt,  // (B*Q, 384) bf16
    const float* __restrict__ refp,             // (BN, Q, 2)
    const void* __restrict__ maskp,             // (BN, Q) bool
    const int* __restrict__ flag,
    unsigned short* __restrict__ S,             // (B*Q, 256) bf16
    float* __restrict__ cnts)                   // (B*Q)
{
    __shared__ int4   sidx[4][NHEAD][17];
    __shared__ float4 swt[4][NHEAD][17];
    __shared__ float  red[4][CDIM];
    __shared__ float  smv[4];
    const int tid  = threadIdx.x;
    const int wn   = tid >> 6;           // wave id = view n
    const int lane = tid & 63;
    const int bq   = blockIdx.x;         // B*Q index
    const int b    = bq >> 13;
    const int q    = bq & (QQ - 1);
    const int bn   = b * 4 + wn;

    const float mn = read_mask(maskp, *flag, (size_t)bn * QQ + q);
    if (lane == 0) smv[wn] = mn;

    const unsigned short* oa = offatt + (size_t)bq * 384;
    const float rx = refp[((size_t)bn * QQ + q) * 2 + 0];
    const float ry = refp[((size_t)bn * QQ + q) * 2 + 1];

    // ---- phase 1: 2 combos per lane; inline softmax over 16-lane groups ----
    #pragma unroll
    for (int cc = 0; cc < 2; ++cc) {
        const int c = lane + cc * 64;        // c = h*16 + l*4 + p
        const int hcomb = c >> 4;
        const int pcomb = c & 15;
        const int l = (c >> 2) & 3;
        const int hh = 64 >> l;
        const int ww = 112 >> l;
        const int s  = (l > 0 ? 7168 : 0) + (l > 1 ? 1792 : 0) + (l > 2 ? 448 : 0);
        const unsigned offxy = *(const unsigned*)(oa + c * 2);
        const float offx = __uint_as_float(offxy << 16);
        const float offy = __uint_as_float(offxy & 0xffff0000u);
        const float logit = bf2f(oa[256 + c]);
        float mx = logit;
        #pragma unroll
        for (int d = 1; d < 16; d <<= 1) mx = fmaxf(mx, __shfl_xor(mx, d));
        const float e = __expf(logit - mx);
        float se = e;
        #pragma unroll
        for (int d = 1; d < 16; d <<= 1) se += __shfl_xor(se, d);
        const float aw = e / se;

        const float x = rx * (float)ww - 0.5f + offx;
        const float y = ry * (float)hh - 0.5f + offy;
        const float x0f = floorf(x), y0f = floorf(y);
        const float lx = x - x0f, ly = y - y0f;
        const int x0 = (int)x0f, y0 = (int)y0f;
        const int x1 = x0 + 1,  y1 = y0 + 1;
        const bool vx0 = (x0 >= 0) & (x0 < ww);
        const bool vx1 = (x1 >= 0) & (x1 < ww);
        const bool vy0 = (y0 >= 0) & (y0 < hh);
        const bool vy1 = (y1 >= 0) & (y1 < hh);
        const int xc0 = min(max(x0, 0), ww - 1);
        const int xc1 = min(max(x1, 0), ww - 1);
        const int yc0 = min(max(y0, 0), hh - 1);
        const int yc1 = min(max(y1, 0), hh - 1);
        float w00 = (1.f - ly) * (1.f - lx) * aw;
        float w01 = (1.f - ly) * lx * aw;
        float w10 = ly * (1.f - lx) * aw;
        float w11 = ly * lx * aw;
        w00 = (vy0 & vx0) ? w00 : 0.f;
        w01 = (vy0 & vx1) ? w01 : 0.f;
        w10 = (vy1 & vx0) ? w10 : 0.f;
        w11 = (vy1 & vx1) ? w11 : 0.f;
        sidx[wn][hcomb][pcomb] = make_int4(s + yc0 * ww + xc0, s + yc0 * ww + xc1,
                                           s + yc1 * ww + xc0, s + yc1 * ww + xc1);
        swt[wn][hcomb][pcomb]  = make_float4(w00, w01, w10, w11);
    }
    // no barrier: phase 2 reads only this wave's [wn] slices (intra-wave dep)

    // ---- phase 2 (live waves only): gather (head-major v). lane = h*8+d4 ----
    f32x2 c01[4], c23[4];
    #pragma unroll
    for (int k = 0; k < 4; ++k) { c01[k] = (f32x2){0.f, 0.f}; c23[k] = (f32x2){0.f, 0.f}; }
    if (mn != 0.f) {
        const int h  = lane >> 3;
        const int d4 = lane & 7;
        // base pre-offset by (bn, h, d4): addr = base + pix*8 (u64 units)
        const unsigned long long* vb = (const unsigned long long*)v
            + (size_t)bn * (NHEAD * NV * 8) + (size_t)h * (NV * 8) + d4;
        #pragma unroll
        for (int pb = 0; pb < 4; ++pb) {
            unsigned long long gld[16];
            float4 wts[4];
            #pragma unroll
            for (int j = 0; j < 4; ++j) {
                const int p = pb * 4 + j;
                const int4 id = sidx[wn][h][p];
                wts[j] = swt[wn][h][p];
                gld[j * 4 + 0] = vb[(size_t)id.x * 8];
                gld[j * 4 + 1] = vb[(size_t)id.y * 8];
                gld[j * 4 + 2] = vb[(size_t)id.z * 8];
                gld[j * 4 + 3] = vb[(size_t)id.w * 8];
            }
            #pragma unroll
            for (int j = 0; j < 4; ++j) {
                const float4 wt = wts[j];
                const float wa[4] = {wt.x, wt.y, wt.z, wt.w};
                #pragma unroll
                for (int cidx = 0; cidx < 4; ++cidx) {
                    const unsigned long long gg = gld[j * 4 + cidx];
                    const unsigned glo = (unsigned)gg;
                    const unsigned ghi = (unsigned)(gg >> 32);
                    const f32x2 wv = (f32x2){wa[cidx], wa[cidx]};
                    #define BFLO(u) __uint_as_float((u) << 16)
                    #define BFHI(u) __uint_as_float((u) & 0xffff0000u)
                    c01[cidx] += wv * (f32x2){BFLO(glo), BFHI(glo)};
                    c23[cidx] += wv * (f32x2){BFLO(ghi), BFHI(ghi)};
                    #undef BFLO
                    #undef BFHI
                }
            }
        }
    }
    const f32x2 acc01 = (c01[0] + c01[1]) + (c01[2] + c01[3]);
    const f32x2 acc23 = (c23[0] + c23[1]) + (c23[2] + c23[3]);
    // lane (h,d4) covers channels h*32 + d4*4 .. +4
    *(float4*)&red[wn][(lane >> 3) * 32 + (lane & 7) * 4] =
        make_float4(acc01.x, acc01.y, acc23.x, acc23.y);
    __syncthreads();

    const float ssum = red[0][tid] + red[1][tid] + red[2][tid] + red[3][tid];
    S[(size_t)bq * CDIM + tid] = f2bf(ssum);
    if (tid == 0) cnts[bq] = smv[0] + smv[1] + smv[2] + smv[3];
}

extern "C" void kernel_launch(void* const* d_in, const int* in_sizes, int n_in,
                              void* d_out, int out_size, void* d_ws, size_t ws_size,
                              hipStream_t stream)
{
    (void)in_sizes; (void)n_in; (void)out_size; (void)ws_size;
    const float* query = (const float*)d_in[0];   // (16384,256)
    const float* value = (const float*)d_in[1];   // (8,9520,256)
    const float* refp  = (const float*)d_in[2];   // (8,8192,2)
    const void*  maskp = d_in[3];                 // (8,8192) bool
    const float* Wv    = (const float*)d_in[6];
    const float* bv    = (const float*)d_in[7];
    const float* Woff  = (const float*)d_in[8];   // (256,256)
    const float* boff  = (const float*)d_in[9];
    const float* Watt  = (const float*)d_in[10];  // (256,128)
    const float* batt  = (const float*)d_in[11];
    const float* Wo    = (const float*)d_in[12];
    const float* bo    = (const float*)d_in[13];
    float* out = (float*)d_out;
    char* ws = (char*)d_ws;

    // workspace layout (bytes)
    unsigned short* v_proj  = (unsigned short*)(ws + 0);          // 38,993,920
    unsigned short* offatt  = (unsigned short*)(ws + 38993920);   // 12,582,912
    unsigned short* S_bf16  = (unsigned short*)(ws + 51576832);   //  8,388,608
    unsigned short* Wt_v    = (unsigned short*)(ws + 59965440);   //    131,072
    unsigned short* Wt_oa   = (unsigned short*)(ws + 60096512);   //    262,144
    unsigned short* Wt_o    = (unsigned short*)(ws + 60358656);   //    131,072
    float*          bias_oa = (float*)(ws + 60489728);            //      2,048
    float*          cnts    = (float*)(ws + 60491776);            //     65,536
    int*            flag    = (int*)(ws + 60557312);              //          4

    pack_weights_detect_kernel<<<1025, 256, 0, stream>>>(
        Wv, Woff, boff, Watt, batt, Wo, (const unsigned int*)maskp,
        Wt_v, Wt_oa, Wt_o, bias_oa, flag);

    // one launch: v_proj (595) + offatt off (128) + offatt att (128)
    mega_gemm_kernel<<<851, 512, 0, stream>>>(
        value, query, Wt_v, Wt_oa, bv, bias_oa, v_proj, offatt);

    // fused softmax + sampling + masked reduce -> S (bf16), cnts
    sample_reduce_kernel<<<16384, 256, 0, stream>>>(
        v_proj, offatt, refp, maskp, flag, S_bf16, cnts);

    // out = (sm*(query+bo) + S@Wo) / max(sm,1)   tile 64x256, full fill
    wo_final_kernel<<<256, 256, 0, stream>>>(
        S_bf16, Wt_o, query, bo, cnts, out);
}